// Round 4
// baseline (236.426 us; speedup 1.0000x reference)
//
#include <hip/hip_runtime.h>

typedef _Float16 f16_t;
typedef f16_t f16x8 __attribute__((ext_vector_type(8)));
typedef float f32x4 __attribute__((ext_vector_type(4)));

#define DEVI __device__ __forceinline__

constexpr int NB    = 64;
constexpr int NTOK  = 197;
constexpr int NH    = 12;
constexpr int DIM   = 768;
constexpr int M_TOK = NB * NTOK;   // 12608
constexpr int NPAD  = 224;         // 14*16 padded token count
constexpr int VT_LD = 232;         // vt / P row stride (f16 elems), 464B = 29*16B
constexpr float SCALE = 0.125f;    // 64^-0.5

DEVI ushort f2h_bits(float f) { _Float16 h = (_Float16)f; return __builtin_bit_cast(ushort, h); }

DEVI void gload16(const void* g, void* l) {
    __builtin_amdgcn_global_load_lds((const __attribute__((address_space(1))) void*)g,
                                     (__attribute__((address_space(3))) void*)l, 16, 0, 0);
}

// ---------------- fp32 -> fp16 convert ----------------
__global__ __launch_bounds__(256) void k_cvt(const float* __restrict__ in, ushort* __restrict__ out, int n4) {
    int i = blockIdx.x * 256 + threadIdx.x;
    if (i >= n4) return;
    float4 v = reinterpret_cast<const float4*>(in)[i];
    ushort4 o;
    o.x = f2h_bits(v.x); o.y = f2h_bits(v.y); o.z = f2h_bits(v.z); o.w = f2h_bits(v.w);
    reinterpret_cast<ushort4*>(out)[i] = o;
}

// ---------------- rel-pos bias gather (mask baked into pad cols) ----------------
__global__ __launch_bounds__(256) void k_bias(const float* __restrict__ rel_table,
                                              const int* __restrict__ rel_index,
                                              float* __restrict__ bias) {
    int idx = blockIdx.x * 256 + threadIdx.x;
    if (idx >= NH * NTOK * NPAD) return;
    int j = idx % NPAD;
    int rem = idx / NPAD;
    int i = rem % NTOK;
    int h = rem / NTOK;
    float v = -1e30f;
    if (j < NTOK) v = rel_table[rel_index[i * NTOK + j] * NH + h];
    bias[idx] = v;
}

// ---------------- 256x256 BT GEMM, BK=64, 8 waves, dbuf LDS + st_16x32 swizzle ----------------
template<int EPI>
__global__ __launch_bounds__(512, 2) void k_gemm8(const ushort* __restrict__ A, const ushort* __restrict__ BT,
                                                  int M, int N, int K,
                                                  const float* __restrict__ b_q, const float* __restrict__ b_v,
                                                  const float* __restrict__ b_p,
                                                  ushort* __restrict__ out_h, float* __restrict__ out_f) {
    extern __shared__ ushort lds[];  // 65536 ushorts = 128 KiB
    const int tid = threadIdx.x, wid = tid >> 6, lane = tid & 63;
    const int wm = wid >> 2, wn = wid & 3;          // 2 x 4 wave grid, wave tile 128x64
    const int fr = lane & 15, fg = lane >> 4;
    const int m0 = blockIdx.y * 256, n0 = blockIdx.x * 256;

    int rowAg[4], rowBg[4], colo[4];
#pragma unroll
    for (int i = 0; i < 4; ++i) {
        const int gl = i * 512 + tid;                    // linear LDS granule (16B) within tile
        const int gs = gl ^ (((gl >> 5) & 1) << 1);      // inverse-swizzled logical granule
        const int r = gs >> 3;
        colo[i] = (gs & 7) * 8;                          // ushort offset within row
        const int ra = m0 + r;
        rowAg[i] = ra < M ? ra : M - 1;                  // clamp (stores masked)
        rowBg[i] = n0 + r;                               // N multiple of 256
    }
    const int ldsoff = wid * 512;                        // wave chunk (64 granules) in ushorts

    f32x4 acc[8][4] = {};
    const int nt = K / 64;

#pragma unroll
    for (int i = 0; i < 4; ++i)
        gload16(A + (size_t)rowAg[i] * K + colo[i], lds + i * 4096 + ldsoff);
#pragma unroll
    for (int i = 0; i < 4; ++i)
        gload16(BT + (size_t)rowBg[i] * K + colo[i], lds + 32768 + i * 4096 + ldsoff);
    __syncthreads();

    for (int t = 0; t < nt; ++t) {
        const int cur = t & 1;
        if (t + 1 < nt) {
            const int nb = cur ^ 1;
            const int k0 = (t + 1) * 64;
#pragma unroll
            for (int i = 0; i < 4; ++i)
                gload16(A + (size_t)rowAg[i] * K + k0 + colo[i], lds + nb * 16384 + i * 4096 + ldsoff);
#pragma unroll
            for (int i = 0; i < 4; ++i)
                gload16(BT + (size_t)rowBg[i] * K + k0 + colo[i], lds + 32768 + nb * 16384 + i * 4096 + ldsoff);
        }
        const char* As = (const char*)(lds + cur * 16384);
        const char* Bs = (const char*)(lds + 32768 + cur * 16384);
#pragma unroll
        for (int q = 0; q < 4; ++q) {
            const int mh = q >> 1, nh = q & 1;
            f16x8 av[4][2], bv[2][2];
#pragma unroll
            for (int mi = 0; mi < 4; ++mi) {
                const int r = wm * 128 + (mh * 4 + mi) * 16 + fr;
                const int base = r * 128 + fg * 16;
                const int sw = (r & 4) << 3;
#pragma unroll
                for (int ks = 0; ks < 2; ++ks)
                    av[mi][ks] = *(const f16x8*)(As + ((base + ks * 64) ^ sw));
            }
#pragma unroll
            for (int ni = 0; ni < 2; ++ni) {
                const int c = wn * 64 + (nh * 2 + ni) * 16 + fr;
                const int base = c * 128 + fg * 16;
                const int sw = (c & 4) << 3;
#pragma unroll
                for (int ks = 0; ks < 2; ++ks)
                    bv[ni][ks] = *(const f16x8*)(Bs + ((base + ks * 64) ^ sw));
            }
#pragma unroll
            for (int ks = 0; ks < 2; ++ks)
#pragma unroll
                for (int mi = 0; mi < 4; ++mi)
#pragma unroll
                    for (int ni = 0; ni < 2; ++ni)
                        acc[mh * 4 + mi][nh * 2 + ni] = __builtin_amdgcn_mfma_f32_16x16x32_f16(
                            av[mi][ks], bv[ni][ks], acc[mh * 4 + mi][nh * 2 + ni], 0, 0, 0);
        }
        __syncthreads();
    }

#pragma unroll
    for (int nf = 0; nf < 4; ++nf) {
        const int col = n0 + wn * 64 + nf * 16 + fr;
        float addv = 0.f, mul = 1.f;
        if (EPI == 0) {
            if (col < 768)       { addv = b_q[col]; mul = SCALE; }
            else if (col < 1536) { addv = 0.f; }
            else                 { addv = b_v[col - 1536]; }
        } else {
            addv = b_p[col];
        }
#pragma unroll
        for (int mf = 0; mf < 8; ++mf) {
#pragma unroll
            for (int rr = 0; rr < 4; ++rr) {
                const int row = m0 + wm * 128 + mf * 16 + fg * 4 + rr;
                if (row < M) {
                    float v = (acc[mf][nf][rr] + addv) * mul;
                    if (EPI == 0) out_h[(size_t)row * N + col] = f2h_bits(v);
                    else          out_f[(size_t)row * N + col] = v;
                }
            }
        }
    }
}

// ---------------- V transpose: qkv v-slice [197][64] -> vt [b,h][64][VT_LD] (zero-padded) ---------
__global__ __launch_bounds__(256) void k_vt(const ushort* __restrict__ qkv, ushort* __restrict__ vt) {
    constexpr int LD = 72;
    __shared__ __align__(16) ushort tile[NPAD * LD];
    const int bh = blockIdx.x;
    const int b = bh / NH, h = bh % NH;
    const size_t base = (size_t)(b * NTOK) * 2304 + 1536 + h * 64;
    for (int t = threadIdx.x; t < NPAD * 8; t += 256) {
        const int row = t >> 3, seg = t & 7;
        uint4 val = make_uint4(0u, 0u, 0u, 0u);
        if (row < NTOK) val = *reinterpret_cast<const uint4*>(qkv + base + (size_t)row * 2304 + seg * 8);
        *reinterpret_cast<uint4*>(tile + row * LD + seg * 8) = val;
    }
    __syncthreads();
    ushort* outp = vt + (size_t)bh * (64 * VT_LD);
    for (int t = threadIdx.x; t < 64 * 29; t += 256) {
        const int d = t / 29, c = t % 29;
        uint w0 = 0, w1 = 0, w2 = 0, w3 = 0;
        if (c < 28) {
            const int nb = c * 8;
            w0 = (uint)tile[(nb + 0) * LD + d] | ((uint)tile[(nb + 1) * LD + d] << 16);
            w1 = (uint)tile[(nb + 2) * LD + d] | ((uint)tile[(nb + 3) * LD + d] << 16);
            w2 = (uint)tile[(nb + 4) * LD + d] | ((uint)tile[(nb + 5) * LD + d] << 16);
            w3 = (uint)tile[(nb + 6) * LD + d] | ((uint)tile[(nb + 7) * LD + d] << 16);
        }
        *reinterpret_cast<uint4*>(outp + (size_t)d * VT_LD + c * 8) = make_uint4(w0, w1, w2, w3);
    }
}

// ---------------- fused attention v2: block = (b,h), 8 waves, K/VT staged ONCE ----------------
// LDS: kp[224][72] | vts[64][232] | ps[8 waves][16][232] (wave-private P)
// After the single barrier, kp/vts are read-only; ps is wave-private -> NO barriers in strip loop.
__global__ __launch_bounds__(512) void k_attn(const ushort* __restrict__ qkv, const ushort* __restrict__ vt,
                                              const float* __restrict__ bias, ushort* __restrict__ out) {
    constexpr int KLD = 72;
    extern __shared__ ushort sm[];
    ushort* kp  = sm;                       // 224*72   = 16128 ushorts
    ushort* vts = sm + NPAD * KLD;          // 64*232   = 14848
    ushort* ps  = vts + 64 * VT_LD;         // 8*16*232 = 29696
    const int tid = threadIdx.x, wid = tid >> 6, lane = tid & 63;
    const int fr = lane & 15, fg = lane >> 4;
    const int bh = blockIdx.x;
    const int b = bh / NH, h = bh % NH;
    const size_t qb = (size_t)(b * NTOK) * 2304;

    // K -> LDS (rows >=197 zeroed)
    for (int t = tid; t < NPAD * 8; t += 512) {
        const int row = t >> 3, seg = t & 7;
        uint4 val = make_uint4(0u, 0u, 0u, 0u);
        if (row < NTOK) val = *reinterpret_cast<const uint4*>(qkv + qb + (size_t)row * 2304 + 768 + h * 64 + seg * 8);
        *reinterpret_cast<uint4*>(kp + row * KLD + seg * 8) = val;
    }
    // VT -> LDS (flat copy)
    const ushort* vtg = vt + (size_t)bh * (64 * VT_LD);
    for (int t = tid; t < 64 * 29; t += 512)
        *reinterpret_cast<uint4*>(vts + t * 8) = *reinterpret_cast<const uint4*>(vtg + t * 8);
    __syncthreads();

    ushort* pw = ps + wid * 16 * VT_LD;     // wave-private P[16][232]

    for (int s = wid; s < 13; s += 8) {     // 13 strips of 16 q-rows cover 197
        const int q0 = s * 16;
        // Q fragments from global (row-clamped; clamped rows' stores are masked)
        f16x8 qf[2];
        {
            int row = q0 + fr;
            row = row < NTOK ? row : NTOK - 1;
            const ushort* qp = qkv + qb + (size_t)row * 2304 + h * 64 + fg * 8;
            qf[0] = *reinterpret_cast<const f16x8*>(qp);
            qf[1] = *reinterpret_cast<const f16x8*>(qp + 32);
        }
        // S = Q K^T
        f32x4 sacc[14] = {};
#pragma unroll
        for (int j = 0; j < 14; ++j) {
#pragma unroll
            for (int kh = 0; kh < 2; ++kh) {
                f16x8 kf = *reinterpret_cast<const f16x8*>(kp + (j * 16 + fr) * KLD + kh * 32 + fg * 8);
                sacc[j] = __builtin_amdgcn_mfma_f32_16x16x32_f16(qf[kh], kf, sacc[j], 0, 0, 0);
            }
        }
        // bias + masked softmax; P -> wave-private LDS
        float rs4[4];
#pragma unroll
        for (int r = 0; r < 4; ++r) {
            const int qrow_l = fg * 4 + r;
            int qrow = q0 + qrow_l;
            qrow = qrow < NTOK ? qrow : NTOK - 1;
            const float* bp = bias + (size_t)(h * NTOK + qrow) * NPAD + fr;
            float mx = -1e30f;
#pragma unroll
            for (int j = 0; j < 14; ++j) {
                float v = sacc[j][r] + bp[j * 16];
                sacc[j][r] = v;
                mx = fmaxf(mx, v);
            }
            mx = fmaxf(mx, __shfl_xor(mx, 1));
            mx = fmaxf(mx, __shfl_xor(mx, 2));
            mx = fmaxf(mx, __shfl_xor(mx, 4));
            mx = fmaxf(mx, __shfl_xor(mx, 8));
            float sum = 0.f;
            ushort* prow = pw + qrow_l * VT_LD;
#pragma unroll
            for (int j = 0; j < 14; ++j) {
                float p = __expf(sacc[j][r] - mx);
                sum += p;
                prow[j * 16 + fr] = f2h_bits(p);
            }
            sum += __shfl_xor(sum, 1);
            sum += __shfl_xor(sum, 2);
            sum += __shfl_xor(sum, 4);
            sum += __shfl_xor(sum, 8);
            rs4[r] = sum;
        }
        // O = P V  (wave-internal RAW on pw: compiler inserts lgkmcnt)
        f32x4 o[4] = {};
#pragma unroll
        for (int kc = 0; kc < 7; ++kc) {
            f16x8 af = *reinterpret_cast<const f16x8*>(pw + fr * VT_LD + kc * 32 + fg * 8);
#pragma unroll
            for (int dt = 0; dt < 4; ++dt) {
                f16x8 bv = *reinterpret_cast<const f16x8*>(vts + (dt * 16 + fr) * VT_LD + kc * 32 + fg * 8);
                o[dt] = __builtin_amdgcn_mfma_f32_16x16x32_f16(af, bv, o[dt], 0, 0, 0);
            }
        }
#pragma unroll
        for (int dt = 0; dt < 4; ++dt) {
#pragma unroll
            for (int r = 0; r < 4; ++r) {
                const int qrow = q0 + fg * 4 + r;
                if (qrow < NTOK) {
                    const float val = o[dt][r] / rs4[r];
                    out[(size_t)(b * NTOK + qrow) * DIM + h * 64 + dt * 16 + fr] = f2h_bits(val);
                }
            }
        }
    }
}

extern "C" void kernel_launch(void* const* d_in, const int* in_sizes, int n_in,
                              void* d_out, int out_size, void* d_ws, size_t ws_size,
                              hipStream_t stream) {
    const float* x         = (const float*)d_in[0];
    const float* Wqkv      = (const float*)d_in[1];
    const float* q_bias    = (const float*)d_in[2];
    const float* v_bias    = (const float*)d_in[3];
    const float* rel_table = (const float*)d_in[4];
    const float* Wproj     = (const float*)d_in[5];
    const float* bproj     = (const float*)d_in[6];
    const int*   rel_index = (const int*)d_in[7];
    float* out = (float*)d_out;

    char* p = (char*)d_ws;
    auto alloc = [&](size_t bytes) { char* r = p; p += (bytes + 255) & ~(size_t)255; return r; };
    ushort* xb     = (ushort*)alloc((size_t)M_TOK * DIM * 2);
    ushort* wqkvb  = (ushort*)alloc((size_t)2304 * 768 * 2);
    ushort* wprojb = (ushort*)alloc((size_t)768 * 768 * 2);
    ushort* qkvb   = (ushort*)alloc((size_t)M_TOK * 2304 * 2);
    ushort* vtb    = (ushort*)alloc((size_t)NB * NH * 64 * VT_LD * 2);
    float*  biasb  = (float*)alloc((size_t)NH * NTOK * NPAD * 4);
    ushort* aob    = (ushort*)alloc((size_t)M_TOK * DIM * 2);

    (void)hipFuncSetAttribute((const void*)k_gemm8<0>, hipFuncAttributeMaxDynamicSharedMemorySize, 131072);
    (void)hipFuncSetAttribute((const void*)k_gemm8<1>, hipFuncAttributeMaxDynamicSharedMemorySize, 131072);
    constexpr int ATTN_LDS = (NPAD * 72 + 64 * VT_LD + 8 * 16 * VT_LD) * 2;  // 121344 B
    (void)hipFuncSetAttribute((const void*)k_attn, hipFuncAttributeMaxDynamicSharedMemorySize, ATTN_LDS);

    int n4 = M_TOK * DIM / 4;
    k_cvt<<<(n4 + 255) / 256, 256, 0, stream>>>(x, xb, n4);
    n4 = 2304 * 768 / 4;
    k_cvt<<<(n4 + 255) / 256, 256, 0, stream>>>(Wqkv, wqkvb, n4);
    n4 = 768 * 768 / 4;
    k_cvt<<<(n4 + 255) / 256, 256, 0, stream>>>(Wproj, wprojb, n4);
    int nbias = NH * NTOK * NPAD;
    k_bias<<<(nbias + 255) / 256, 256, 0, stream>>>(rel_table, rel_index, biasb);

    k_gemm8<0><<<dim3(2304 / 256, (M_TOK + 255) / 256), 512, 131072, stream>>>(
        xb, wqkvb, M_TOK, 2304, 768, q_bias, v_bias, nullptr, qkvb, nullptr);
    k_vt<<<NB * NH, 256, 0, stream>>>(qkvb, vtb);
    k_attn<<<dim3(NB * NH), 512, ATTN_LDS, stream>>>(qkvb, vtb, biasb, aob);
    k_gemm8<1><<<dim3(768 / 256, (M_TOK + 255) / 256), 512, 131072, stream>>>(
        aob, wprojb, M_TOK, 768, 768, nullptr, nullptr, bproj, nullptr, out);
}

// Round 5
// 214.617 us; speedup vs baseline: 1.1016x; 1.1016x over previous
//
#include <hip/hip_runtime.h>

typedef _Float16 f16_t;
typedef f16_t f16x8 __attribute__((ext_vector_type(8)));
typedef float f32x4 __attribute__((ext_vector_type(4)));

#define DEVI __device__ __forceinline__

constexpr int NB    = 64;
constexpr int NTOK  = 197;
constexpr int NH    = 12;
constexpr int DIM   = 768;
constexpr int M_TOK = NB * NTOK;   // 12608
constexpr int NPAD  = 224;         // 14*16 padded token count
constexpr int VT_LD = 232;         // vt / P row stride (f16 elems), 464B = 29*16B
constexpr float SCALE = 0.125f;    // 64^-0.5

DEVI ushort f2h_bits(float f) { _Float16 h = (_Float16)f; return __builtin_bit_cast(ushort, h); }

DEVI void gload16(const void* g, void* l) {
    __builtin_amdgcn_global_load_lds((const __attribute__((address_space(1))) void*)g,
                                     (__attribute__((address_space(3))) void*)l, 16, 0, 0);
}

// ---------------- fp32 -> fp16 convert ----------------
__global__ __launch_bounds__(256) void k_cvt(const float* __restrict__ in, ushort* __restrict__ out, int n4) {
    int i = blockIdx.x * 256 + threadIdx.x;
    if (i >= n4) return;
    float4 v = reinterpret_cast<const float4*>(in)[i];
    ushort4 o;
    o.x = f2h_bits(v.x); o.y = f2h_bits(v.y); o.z = f2h_bits(v.z); o.w = f2h_bits(v.w);
    reinterpret_cast<ushort4*>(out)[i] = o;
}

// ---------------- rel-pos bias gather, f16, FRAGMENT-ORDERED [h][qrow][fr][16] ----------------
// attn lane (fr,fg) row qrow reads elems j=0..13 (col = j*16+fr) as two f16x8 vector loads.
__global__ __launch_bounds__(256) void k_bias(const float* __restrict__ rel_table,
                                              const int* __restrict__ rel_index,
                                              ushort* __restrict__ biash) {
    int idx = blockIdx.x * 256 + threadIdx.x;
    if (idx >= NH * NPAD * 256) return;
    const int j  = idx & 15;
    const int fr = (idx >> 4) & 15;
    const int i  = (idx >> 8) % NPAD;
    const int h  = (idx >> 8) / NPAD;
    const int col = j * 16 + fr;
    float v = -30000.f;   // f16-finite mask value; exp(v - mx) == 0
    if (i < NTOK && col < NTOK && j < 14) v = rel_table[rel_index[i * NTOK + col] * NH + h];
    biash[idx] = f2h_bits(v);
}

// ---------------- 128x128 BT GEMM, BK=32, dbuf (32KB LDS), 4 waves, XOR-swizzled ----------------
// 2-phase prefetch; ~4-5 blocks/CU co-resident so the per-barrier vmcnt drain overlaps with
// other blocks' MFMA (m97/m114 mechanism). Swizzle for 64B rows: phys_seg = seg ^ ((row>>1)&3)
// (rows 0..7 cover all 32 banks disjointly -> 2-way on ds_read_b128 = free). Involution applied
// as inverse-permuted GLOBAL SOURCE granule (gload_lds dest stays linear) + XOR'd read address.
template<int EPI>
__global__ __launch_bounds__(256) void k_gemm(const ushort* __restrict__ A, const ushort* __restrict__ BT,
                                              int M, int N, int K,
                                              const float* __restrict__ b_q, const float* __restrict__ b_v,
                                              const float* __restrict__ b_p,
                                              ushort* __restrict__ out_h, float* __restrict__ out_f) {
    __shared__ __align__(16) ushort lds[2][8192];   // [dbuf][A:0..4095 | B:4096..8191]
    const int tid = threadIdx.x, wid = tid >> 6, lane = tid & 63;
    const int wm = wid >> 1, wn = wid & 1;
    const int fr = lane & 15, fg = lane >> 4;
    const int m0 = blockIdx.y * 128, n0 = blockIdx.x * 128;

    // staging maps: 2 issues per operand per wave; granule g=(wid*2+i)*64+lane
    int rA[2], rB[2], cs[2], dst[2];
#pragma unroll
    for (int i = 0; i < 2; ++i) {
        const int g = (wid * 2 + i) * 64 + lane;
        const int row = g >> 2, sp = g & 3;
        cs[i]  = (sp ^ ((row >> 1) & 3)) * 8;        // source ushort-col within K-tile
        dst[i] = (wid * 2 + i) * 512;                // wave-uniform LDS base (ushorts)
        const int ra = m0 + row;
        rA[i] = ra < M ? ra : M - 1;                 // clamp tail (stores masked)
        rB[i] = n0 + row;                            // N multiple of 128
    }

    f32x4 acc[4][4] = {};
    const int nt = K / 32;

    auto stage = [&](int t, int buf) {
#pragma unroll
        for (int i = 0; i < 2; ++i)
            gload16(A + (size_t)rA[i] * K + t * 32 + cs[i], &lds[buf][dst[i]]);
#pragma unroll
        for (int i = 0; i < 2; ++i)
            gload16(BT + (size_t)rB[i] * K + t * 32 + cs[i], &lds[buf][4096 + dst[i]]);
    };

    stage(0, 0);
    __syncthreads();
    for (int t = 0; t < nt; ++t) {
        const int cur = t & 1;
        if (t + 1 < nt) stage(t + 1, cur ^ 1);
        const ushort* As = lds[cur];
        const ushort* Bs = lds[cur] + 4096;
        f16x8 af[4], bf[4];
#pragma unroll
        for (int i = 0; i < 4; ++i) {
            const int r = wm * 64 + i * 16 + fr;
            af[i] = *(const f16x8*)(As + r * 32 + ((fg ^ ((r >> 1) & 3)) * 8));
        }
#pragma unroll
        for (int i = 0; i < 4; ++i) {
            const int c = wn * 64 + i * 16 + fr;
            bf[i] = *(const f16x8*)(Bs + c * 32 + ((fg ^ ((c >> 1) & 3)) * 8));
        }
#pragma unroll
        for (int mi = 0; mi < 4; ++mi)
#pragma unroll
            for (int ni = 0; ni < 4; ++ni)
                acc[mi][ni] = __builtin_amdgcn_mfma_f32_16x16x32_f16(af[mi], bf[ni], acc[mi][ni], 0, 0, 0);
        __syncthreads();
    }

#pragma unroll
    for (int ni = 0; ni < 4; ++ni) {
        const int col = n0 + wn * 64 + ni * 16 + fr;
        float addv = 0.f, mul = 1.f;
        if (EPI == 0) {
            if (col < 768)       { addv = b_q[col]; mul = SCALE; }
            else if (col < 1536) { addv = 0.f; }
            else                 { addv = b_v[col - 1536]; }
        } else {
            addv = b_p[col];
        }
#pragma unroll
        for (int mi = 0; mi < 4; ++mi) {
#pragma unroll
            for (int r = 0; r < 4; ++r) {
                const int row = m0 + wm * 64 + mi * 16 + fg * 4 + r;
                if (row < M) {
                    float v = (acc[mi][ni][r] + addv) * mul;
                    if (EPI == 0) out_h[(size_t)row * N + col] = f2h_bits(v);
                    else          out_f[(size_t)row * N + col] = v;
                }
            }
        }
    }
}

// ---------------- V transpose: qkv v-slice [197][64] -> vt [b,h][64][VT_LD] (zero-padded) ---------
__global__ __launch_bounds__(256) void k_vt(const ushort* __restrict__ qkv, ushort* __restrict__ vt) {
    constexpr int LD = 72;
    __shared__ __align__(16) ushort tile[NPAD * LD];
    const int bh = blockIdx.x;
    const int b = bh / NH, h = bh % NH;
    const size_t base = (size_t)(b * NTOK) * 2304 + 1536 + h * 64;
    for (int t = threadIdx.x; t < NPAD * 8; t += 256) {
        const int row = t >> 3, seg = t & 7;
        uint4 val = make_uint4(0u, 0u, 0u, 0u);
        if (row < NTOK) val = *reinterpret_cast<const uint4*>(qkv + base + (size_t)row * 2304 + seg * 8);
        *reinterpret_cast<uint4*>(tile + row * LD + seg * 8) = val;
    }
    __syncthreads();
    ushort* outp = vt + (size_t)bh * (64 * VT_LD);
    for (int t = threadIdx.x; t < 64 * 29; t += 256) {
        const int d = t / 29, c = t % 29;
        uint w0 = 0, w1 = 0, w2 = 0, w3 = 0;
        if (c < 28) {
            const int nb = c * 8;
            w0 = (uint)tile[(nb + 0) * LD + d] | ((uint)tile[(nb + 1) * LD + d] << 16);
            w1 = (uint)tile[(nb + 2) * LD + d] | ((uint)tile[(nb + 3) * LD + d] << 16);
            w2 = (uint)tile[(nb + 4) * LD + d] | ((uint)tile[(nb + 5) * LD + d] << 16);
            w3 = (uint)tile[(nb + 6) * LD + d] | ((uint)tile[(nb + 7) * LD + d] << 16);
        }
        *reinterpret_cast<uint4*>(outp + (size_t)d * VT_LD + c * 8) = make_uint4(w0, w1, w2, w3);
    }
}

// ---------------- fused attention: block = (b,h), 8 waves, K/VT staged ONCE ----------------
__global__ __launch_bounds__(512) void k_attn(const ushort* __restrict__ qkv, const ushort* __restrict__ vt,
                                              const ushort* __restrict__ biash, ushort* __restrict__ out) {
    constexpr int KLD = 72;
    extern __shared__ ushort sm[];
    ushort* kp  = sm;                       // 224*72   = 16128 ushorts
    ushort* vts = sm + NPAD * KLD;          // 64*232   = 14848
    ushort* ps  = vts + 64 * VT_LD;         // 8*16*232 = 29696
    const int tid = threadIdx.x, wid = tid >> 6, lane = tid & 63;
    const int fr = lane & 15, fg = lane >> 4;
    const int bh = blockIdx.x;
    const int b = bh / NH, h = bh % NH;
    const size_t qb = (size_t)(b * NTOK) * 2304;

    for (int t = tid; t < NPAD * 8; t += 512) {
        const int row = t >> 3, seg = t & 7;
        uint4 val = make_uint4(0u, 0u, 0u, 0u);
        if (row < NTOK) val = *reinterpret_cast<const uint4*>(qkv + qb + (size_t)row * 2304 + 768 + h * 64 + seg * 8);
        *reinterpret_cast<uint4*>(kp + row * KLD + seg * 8) = val;
    }
    const ushort* vtg = vt + (size_t)bh * (64 * VT_LD);
    for (int t = tid; t < 64 * 29; t += 512)
        *reinterpret_cast<uint4*>(vts + t * 8) = *reinterpret_cast<const uint4*>(vtg + t * 8);
    __syncthreads();

    ushort* pw = ps + wid * 16 * VT_LD;

    for (int s = wid; s < 13; s += 8) {
        const int q0 = s * 16;
        f16x8 qf[2];
        {
            int row = q0 + fr;
            row = row < NTOK ? row : NTOK - 1;
            const ushort* qp = qkv + qb + (size_t)row * 2304 + h * 64 + fg * 8;
            qf[0] = *reinterpret_cast<const f16x8*>(qp);
            qf[1] = *reinterpret_cast<const f16x8*>(qp + 32);
        }
        f32x4 sacc[14] = {};
#pragma unroll
        for (int j = 0; j < 14; ++j) {
#pragma unroll
            for (int kh = 0; kh < 2; ++kh) {
                f16x8 kf = *reinterpret_cast<const f16x8*>(kp + (j * 16 + fr) * KLD + kh * 32 + fg * 8);
                sacc[j] = __builtin_amdgcn_mfma_f32_16x16x32_f16(qf[kh], kf, sacc[j], 0, 0, 0);
            }
        }
        float rs4[4];
#pragma unroll
        for (int r = 0; r < 4; ++r) {
            const int qrow_l = fg * 4 + r;
            int qrow = q0 + qrow_l;
            qrow = qrow < NTOK ? qrow : NTOK - 1;
            // fragment-ordered f16 bias: 2 vector loads cover j=0..13
            const ushort* bp16 = biash + (((size_t)(h * NPAD + qrow) * 16 + fr) << 4);
            f16x8 bv0 = *reinterpret_cast<const f16x8*>(bp16);
            f16x8 bv1 = *reinterpret_cast<const f16x8*>(bp16 + 8);
            float mx = -1e30f;
#pragma unroll
            for (int j = 0; j < 14; ++j) {
                const float bj = (float)(j < 8 ? bv0[j] : bv1[j - 8]);
                float v = sacc[j][r] + bj;
                sacc[j][r] = v;
                mx = fmaxf(mx, v);
            }
            mx = fmaxf(mx, __shfl_xor(mx, 1));
            mx = fmaxf(mx, __shfl_xor(mx, 2));
            mx = fmaxf(mx, __shfl_xor(mx, 4));
            mx = fmaxf(mx, __shfl_xor(mx, 8));
            float sum = 0.f;
            ushort* prow = pw + qrow_l * VT_LD;
#pragma unroll
            for (int j = 0; j < 14; ++j) {
                float p = __expf(sacc[j][r] - mx);
                sum += p;
                prow[j * 16 + fr] = f2h_bits(p);
            }
            sum += __shfl_xor(sum, 1);
            sum += __shfl_xor(sum, 2);
            sum += __shfl_xor(sum, 4);
            sum += __shfl_xor(sum, 8);
            rs4[r] = sum;
        }
        f32x4 o[4] = {};
#pragma unroll
        for (int kc = 0; kc < 7; ++kc) {
            f16x8 af = *reinterpret_cast<const f16x8*>(pw + fr * VT_LD + kc * 32 + fg * 8);
#pragma unroll
            for (int dt = 0; dt < 4; ++dt) {
                f16x8 bv = *reinterpret_cast<const f16x8*>(vts + (dt * 16 + fr) * VT_LD + kc * 32 + fg * 8);
                o[dt] = __builtin_amdgcn_mfma_f32_16x16x32_f16(af, bv, o[dt], 0, 0, 0);
            }
        }
#pragma unroll
        for (int dt = 0; dt < 4; ++dt) {
#pragma unroll
            for (int r = 0; r < 4; ++r) {
                const int qrow = q0 + fg * 4 + r;
                if (qrow < NTOK) {
                    const float val = o[dt][r] / rs4[r];
                    out[(size_t)(b * NTOK + qrow) * DIM + h * 64 + dt * 16 + fr] = f2h_bits(val);
                }
            }
        }
    }
}

extern "C" void kernel_launch(void* const* d_in, const int* in_sizes, int n_in,
                              void* d_out, int out_size, void* d_ws, size_t ws_size,
                              hipStream_t stream) {
    const float* x         = (const float*)d_in[0];
    const float* Wqkv      = (const float*)d_in[1];
    const float* q_bias    = (const float*)d_in[2];
    const float* v_bias    = (const float*)d_in[3];
    const float* rel_table = (const float*)d_in[4];
    const float* Wproj     = (const float*)d_in[5];
    const float* bproj     = (const float*)d_in[6];
    const int*   rel_index = (const int*)d_in[7];
    float* out = (float*)d_out;

    char* p = (char*)d_ws;
    auto alloc = [&](size_t bytes) { char* r = p; p += (bytes + 255) & ~(size_t)255; return r; };
    ushort* xb     = (ushort*)alloc((size_t)M_TOK * DIM * 2);
    ushort* wqkvb  = (ushort*)alloc((size_t)2304 * 768 * 2);
    ushort* wprojb = (ushort*)alloc((size_t)768 * 768 * 2);
    ushort* qkvb   = (ushort*)alloc((size_t)M_TOK * 2304 * 2);
    ushort* vtb    = (ushort*)alloc((size_t)NB * NH * 64 * VT_LD * 2);
    ushort* biasb  = (ushort*)alloc((size_t)NH * NPAD * 256 * 2);
    ushort* aob    = (ushort*)alloc((size_t)M_TOK * DIM * 2);

    constexpr int ATTN_LDS = (NPAD * 72 + 64 * VT_LD + 8 * 16 * VT_LD) * 2;  // 121344 B
    (void)hipFuncSetAttribute((const void*)k_attn, hipFuncAttributeMaxDynamicSharedMemorySize, ATTN_LDS);

    int n4 = M_TOK * DIM / 4;
    k_cvt<<<(n4 + 255) / 256, 256, 0, stream>>>(x, xb, n4);
    n4 = 2304 * 768 / 4;
    k_cvt<<<(n4 + 255) / 256, 256, 0, stream>>>(Wqkv, wqkvb, n4);
    n4 = 768 * 768 / 4;
    k_cvt<<<(n4 + 255) / 256, 256, 0, stream>>>(Wproj, wprojb, n4);
    int nbias = NH * NPAD * 256;
    k_bias<<<(nbias + 255) / 256, 256, 0, stream>>>(rel_table, rel_index, biasb);

    k_gemm<0><<<dim3(2304 / 128, (M_TOK + 127) / 128), 256, 0, stream>>>(
        xb, wqkvb, M_TOK, 2304, 768, q_bias, v_bias, nullptr, qkvb, nullptr);
    k_vt<<<NB * NH, 256, 0, stream>>>(qkvb, vtb);
    k_attn<<<dim3(NB * NH), 512, ATTN_LDS, stream>>>(qkvb, vtb, biasb, aob);
    k_gemm<1><<<dim3(768 / 128, (M_TOK + 127) / 128), 256, 0, stream>>>(
        aob, wprojb, M_TOK, 768, 768, nullptr, nullptr, bproj, nullptr, out);
}

// Round 6
// 190.621 us; speedup vs baseline: 1.2403x; 1.1259x over previous
//
#include <hip/hip_runtime.h>

typedef _Float16 f16_t;
typedef f16_t f16x8 __attribute__((ext_vector_type(8)));
typedef float f32x4 __attribute__((ext_vector_type(4)));

#define DEVI __device__ __forceinline__

constexpr int NB    = 64;
constexpr int NTOK  = 197;
constexpr int NH    = 12;
constexpr int DIM   = 768;
constexpr int M_TOK = NB * NTOK;   // 12608
constexpr int NPAD  = 224;         // 14*16 padded token count
constexpr int VT_LD = 232;         // vt / P row stride (f16 elems), 464B = 29*16B
constexpr float SCALE = 0.125f;    // 64^-0.5

DEVI ushort f2h_bits(float f) { _Float16 h = (_Float16)f; return __builtin_bit_cast(ushort, h); }

DEVI void gload16(const void* g, void* l) {
    __builtin_amdgcn_global_load_lds((const __attribute__((address_space(1))) void*)g,
                                     (__attribute__((address_space(3))) void*)l, 16, 0, 0);
}

// ---------------- fp32 -> fp16 convert ----------------
__global__ __launch_bounds__(256) void k_cvt(const float* __restrict__ in, ushort* __restrict__ out, int n4) {
    int i = blockIdx.x * 256 + threadIdx.x;
    if (i >= n4) return;
    float4 v = reinterpret_cast<const float4*>(in)[i];
    ushort4 o;
    o.x = f2h_bits(v.x); o.y = f2h_bits(v.y); o.z = f2h_bits(v.z); o.w = f2h_bits(v.w);
    reinterpret_cast<ushort4*>(out)[i] = o;
}

// ---------------- rel-pos bias gather, f16, FRAGMENT-ORDERED [h][qrow][fr][16] ----------------
__global__ __launch_bounds__(256) void k_bias(const float* __restrict__ rel_table,
                                              const int* __restrict__ rel_index,
                                              ushort* __restrict__ biash) {
    int idx = blockIdx.x * 256 + threadIdx.x;
    if (idx >= NH * NPAD * 256) return;
    const int j  = idx & 15;
    const int fr = (idx >> 4) & 15;
    const int i  = (idx >> 8) % NPAD;
    const int h  = (idx >> 8) / NPAD;
    const int col = j * 16 + fr;
    float v = -30000.f;
    if (i < NTOK && col < NTOK && j < 14) v = rel_table[rel_index[i * NTOK + col] * NH + h];
    biash[idx] = f2h_bits(v);
}

// ================= QKV GEMM: 256x256, BK=64, 8-phase counted-vmcnt schedule =================
// Waves: 2(m) x 4(n), wave tile 128x64. LDS: A[2 buf][2 Khalf][256r x 32c] | B same (128 KiB).
// Per K-tile (4 phases): ph(ks,nh) computes 8mi x 2ni MFMAs at K-slice ks. A-frags read once per
// ks (held 2 phases); B-frags read once. Each phase stages ONE 16KB unit (2 gload_lds/thread):
//   ph1:A1(t0+1) ph2:B1(t0+1) ph3:A0(t0+2) ph4:B0(t0+2) ph5:A1(t0+2) ph6:B1(t0+2)
//   ph7:A0(t0+3) ph8:B0(t0+3)     (unit staged >=1 phase after its previous occupant's last read)
// vmcnt(4) gates ONLY at ph4/ph8 end, BEFORE the barrier (so every wave drains its own loads
// before any wave reads cooperative data). Tail stages wrap to tile 0 (dummies) to keep the
// vmcnt ledger uniform; a full drain precedes the epilogue (dummies land in reused LDS).
// Swizzle (measured conflict-free in r5): 32-col rows, phys_granule = g ^ ((row>>1)&3);
// applied as inverse-permuted GLOBAL SOURCE (linear gload dest) + XOR'd ds_read col.
__global__ __launch_bounds__(512, 2) void k_qkv8(const ushort* __restrict__ A, const ushort* __restrict__ BT,
                                                 const float* __restrict__ b_q, const float* __restrict__ b_v,
                                                 ushort* __restrict__ outp) {
    constexpr int M = M_TOK, N = 2304, K = 768, nt = K / 64;  // nt = 12 (even)
    extern __shared__ ushort lds[];           // 65536 ushorts = 128 KiB
    ushort* ldsA = lds;
    ushort* ldsB = lds + 32768;
    const int tid = threadIdx.x, wid = tid >> 6, lane = tid & 63;
    const int wm = wid >> 2, wn = wid & 3;
    const int fr = lane & 15, fg = lane >> 4;
    const int m0 = blockIdx.y * 256, n0 = blockIdx.x * 256;

    // staging source pointers (swizzle-inverse baked in; same for both granule rows: (r+128)>>1 &3 == r>>1 &3)
    const int srow = tid >> 2;
    const int sc = ((tid & 3) ^ ((tid >> 3) & 3)) * 8;
    int ra0 = m0 + srow;       ra0 = ra0 < M ? ra0 : M - 1;
    int ra1 = m0 + srow + 128; ra1 = ra1 < M ? ra1 : M - 1;
    const ushort* pA0 = A + (size_t)ra0 * K + sc;
    const ushort* pA1 = A + (size_t)ra1 * K + sc;
    const ushort* pB0 = BT + (size_t)(n0 + srow) * K + sc;
    const ushort* pB1 = BT + (size_t)(n0 + srow + 128) * K + sc;
    const int dstt = tid * 8;

    int aoff[8], boff[4];
#pragma unroll
    for (int mi = 0; mi < 8; ++mi) {
        const int r = wm * 128 + mi * 16 + fr;
        aoff[mi] = r * 32 + ((fg ^ ((r >> 1) & 3)) * 8);
    }
#pragma unroll
    for (int j = 0; j < 4; ++j) {
        const int c = wn * 64 + j * 16 + fr;
        boff[j] = c * 32 + ((fg ^ ((c >> 1) & 3)) * 8);
    }

    f32x4 acc[8][4] = {};
    f16x8 av[8];

    auto STAGE = [&](int T, int isA, int k) {
        const int Tw = T >= nt ? T - nt : T;          // tail wrap: dummy re-stage of tile 0/1
        const size_t so = (size_t)(Tw * 64 + k * 32);
        const int db = (T & 1) * 16384 + k * 8192 + dstt;
        if (isA) { gload16(pA0 + so, ldsA + db); gload16(pA1 + so, ldsA + db + 4096); }
        else     { gload16(pB0 + so, ldsB + db); gload16(pB1 + so, ldsB + db + 4096); }
    };

#define LDA8(B_, KS_) { _Pragma("unroll") for (int mi = 0; mi < 8; ++mi) \
        av[mi] = *(const f16x8*)(ldsA + (B_) * 16384 + (KS_) * 8192 + aoff[mi]); }

#define PHASE(B_, KS_, NH_, LA_, ST_T, ST_A, ST_K, GATE_) { \
        if (LA_) LDA8(B_, KS_); \
        f16x8 bv0 = *(const f16x8*)(ldsB + (B_) * 16384 + (KS_) * 8192 + boff[(NH_) * 2]); \
        f16x8 bv1 = *(const f16x8*)(ldsB + (B_) * 16384 + (KS_) * 8192 + boff[(NH_) * 2 + 1]); \
        STAGE(ST_T, ST_A, ST_K); \
        __builtin_amdgcn_s_barrier(); \
        __builtin_amdgcn_s_setprio(1); \
        _Pragma("unroll") for (int mi = 0; mi < 8; ++mi) { \
            acc[mi][(NH_) * 2]     = __builtin_amdgcn_mfma_f32_16x16x32_f16(av[mi], bv0, acc[mi][(NH_) * 2], 0, 0, 0); \
            acc[mi][(NH_) * 2 + 1] = __builtin_amdgcn_mfma_f32_16x16x32_f16(av[mi], bv1, acc[mi][(NH_) * 2 + 1], 0, 0, 0); } \
        __builtin_amdgcn_s_setprio(0); \
        asm volatile("s_waitcnt lgkmcnt(0)" ::: "memory"); \
        __builtin_amdgcn_sched_barrier(0); \
        if (GATE_) { asm volatile("s_waitcnt vmcnt(4)" ::: "memory"); __builtin_amdgcn_sched_barrier(0); } \
        __builtin_amdgcn_s_barrier(); }

    // prologue: tile0 all 4 units + tile1 A0,B0  (12 loads; gate leaves tile1's 4 outstanding)
    STAGE(0, 1, 0); STAGE(0, 0, 0); STAGE(0, 1, 1); STAGE(0, 0, 1);
    STAGE(1, 1, 0); STAGE(1, 0, 0);
    asm volatile("s_waitcnt vmcnt(4)" ::: "memory");
    __builtin_amdgcn_sched_barrier(0);
    __builtin_amdgcn_s_barrier();

    for (int i = 0; i < nt / 2; ++i) {
        const int t0 = 2 * i;
        PHASE(0, 0, 0, 1, t0 + 1, 1, 1, 0)
        PHASE(0, 0, 1, 0, t0 + 1, 0, 1, 0)
        PHASE(0, 1, 0, 1, t0 + 2, 1, 0, 0)
        PHASE(0, 1, 1, 0, t0 + 2, 0, 0, 1)
        PHASE(1, 0, 0, 1, t0 + 2, 1, 1, 0)
        PHASE(1, 0, 1, 0, t0 + 2, 0, 1, 0)
        PHASE(1, 1, 0, 1, t0 + 3, 1, 0, 0)
        PHASE(1, 1, 1, 0, t0 + 3, 0, 0, 1)
    }
#undef PHASE
#undef LDA8

    // drain in-flight dummy stages before reusing LDS as epilogue scratch
    asm volatile("s_waitcnt vmcnt(0) lgkmcnt(0)" ::: "memory");
    __builtin_amdgcn_sched_barrier(0);
    __builtin_amdgcn_s_barrier();

    // epilogue: bias in f32 -> f16 -> wave-private LDS [128][64] -> coalesced 16B stores
    ushort* ws = lds + wid * 8192;
#pragma unroll
    for (int ni = 0; ni < 4; ++ni) {
        const int col = n0 + wn * 64 + ni * 16 + fr;
        float addv, mul;
        if (col < 768)       { addv = b_q[col]; mul = SCALE; }
        else if (col < 1536) { addv = 0.f; mul = 1.f; }
        else                 { addv = b_v[col - 1536]; mul = 1.f; }
#pragma unroll
        for (int mi = 0; mi < 8; ++mi)
#pragma unroll
            for (int r = 0; r < 4; ++r)
                ws[(mi * 16 + fg * 4 + r) * 64 + ni * 16 + fr] = f2h_bits((acc[mi][ni][r] + addv) * mul);
    }
    __syncthreads();   // cross-lane LDS visibility (block-wide is overkill but safe, runs once)
#pragma unroll
    for (int it = 0; it < 16; ++it) {
        const int g = it * 64 + lane;
        const int r = g >> 3, seg = g & 7;
        const int row = m0 + wm * 128 + r;
        uint4 v = *(const uint4*)(ws + r * 64 + seg * 8);
        if (row < M) *(uint4*)(outp + (size_t)row * N + n0 + wn * 64 + seg * 8) = v;
    }
}

// ---------------- 128x128 BT GEMM, BK=32, dbuf, XOR-swizzled (proj) ----------------
template<int EPI>
__global__ __launch_bounds__(256) void k_gemm(const ushort* __restrict__ A, const ushort* __restrict__ BT,
                                              int M, int N, int K,
                                              const float* __restrict__ b_q, const float* __restrict__ b_v,
                                              const float* __restrict__ b_p,
                                              ushort* __restrict__ out_h, float* __restrict__ out_f) {
    __shared__ __align__(16) ushort lds[2][8192];
    const int tid = threadIdx.x, wid = tid >> 6, lane = tid & 63;
    const int wm = wid >> 1, wn = wid & 1;
    const int fr = lane & 15, fg = lane >> 4;
    const int m0 = blockIdx.y * 128, n0 = blockIdx.x * 128;

    int rA[2], rB[2], cs[2], dst[2];
#pragma unroll
    for (int i = 0; i < 2; ++i) {
        const int g = (wid * 2 + i) * 64 + lane;
        const int row = g >> 2, sp = g & 3;
        cs[i]  = (sp ^ ((row >> 1) & 3)) * 8;
        dst[i] = (wid * 2 + i) * 512;
        const int ra = m0 + row;
        rA[i] = ra < M ? ra : M - 1;
        rB[i] = n0 + row;
    }

    f32x4 acc[4][4] = {};
    const int nt = K / 32;

    auto stage = [&](int t, int buf) {
#pragma unroll
        for (int i = 0; i < 2; ++i)
            gload16(A + (size_t)rA[i] * K + t * 32 + cs[i], &lds[buf][dst[i]]);
#pragma unroll
        for (int i = 0; i < 2; ++i)
            gload16(BT + (size_t)rB[i] * K + t * 32 + cs[i], &lds[buf][4096 + dst[i]]);
    };

    stage(0, 0);
    __syncthreads();
    for (int t = 0; t < nt; ++t) {
        const int cur = t & 1;
        if (t + 1 < nt) stage(t + 1, cur ^ 1);
        const ushort* As = lds[cur];
        const ushort* Bs = lds[cur] + 4096;
        f16x8 af[4], bf[4];
#pragma unroll
        for (int i = 0; i < 4; ++i) {
            const int r = wm * 64 + i * 16 + fr;
            af[i] = *(const f16x8*)(As + r * 32 + ((fg ^ ((r >> 1) & 3)) * 8));
        }
#pragma unroll
        for (int i = 0; i < 4; ++i) {
            const int c = wn * 64 + i * 16 + fr;
            bf[i] = *(const f16x8*)(Bs + c * 32 + ((fg ^ ((c >> 1) & 3)) * 8));
        }
#pragma unroll
        for (int mi = 0; mi < 4; ++mi)
#pragma unroll
            for (int ni = 0; ni < 4; ++ni)
                acc[mi][ni] = __builtin_amdgcn_mfma_f32_16x16x32_f16(af[mi], bf[ni], acc[mi][ni], 0, 0, 0);
        __syncthreads();
    }

#pragma unroll
    for (int ni = 0; ni < 4; ++ni) {
        const int col = n0 + wn * 64 + ni * 16 + fr;
        float addv = 0.f, mul = 1.f;
        if (EPI == 0) {
            if (col < 768)       { addv = b_q[col]; mul = SCALE; }
            else if (col < 1536) { addv = 0.f; }
            else                 { addv = b_v[col - 1536]; }
        } else {
            addv = b_p[col];
        }
#pragma unroll
        for (int mi = 0; mi < 4; ++mi) {
#pragma unroll
            for (int r = 0; r < 4; ++r) {
                const int row = m0 + wm * 64 + mi * 16 + fg * 4 + r;
                if (row < M) {
                    float v = (acc[mi][ni][r] + addv) * mul;
                    if (EPI == 0) out_h[(size_t)row * N + col] = f2h_bits(v);
                    else          out_f[(size_t)row * N + col] = v;
                }
            }
        }
    }
}

// ---------------- V transpose: qkv v-slice [197][64] -> vt [b,h][64][VT_LD] (zero-padded) ---------
__global__ __launch_bounds__(256) void k_vt(const ushort* __restrict__ qkv, ushort* __restrict__ vt) {
    constexpr int LD = 72;
    __shared__ __align__(16) ushort tile[NPAD * LD];
    const int bh = blockIdx.x;
    const int b = bh / NH, h = bh % NH;
    const size_t base = (size_t)(b * NTOK) * 2304 + 1536 + h * 64;
    for (int t = threadIdx.x; t < NPAD * 8; t += 256) {
        const int row = t >> 3, seg = t & 7;
        uint4 val = make_uint4(0u, 0u, 0u, 0u);
        if (row < NTOK) val = *reinterpret_cast<const uint4*>(qkv + base + (size_t)row * 2304 + seg * 8);
        *reinterpret_cast<uint4*>(tile + row * LD + seg * 8) = val;
    }
    __syncthreads();
    ushort* outp = vt + (size_t)bh * (64 * VT_LD);
    for (int t = threadIdx.x; t < 64 * 29; t += 256) {
        const int d = t / 29, c = t % 29;
        uint w0 = 0, w1 = 0, w2 = 0, w3 = 0;
        if (c < 28) {
            const int nb = c * 8;
            w0 = (uint)tile[(nb + 0) * LD + d] | ((uint)tile[(nb + 1) * LD + d] << 16);
            w1 = (uint)tile[(nb + 2) * LD + d] | ((uint)tile[(nb + 3) * LD + d] << 16);
            w2 = (uint)tile[(nb + 4) * LD + d] | ((uint)tile[(nb + 5) * LD + d] << 16);
            w3 = (uint)tile[(nb + 6) * LD + d] | ((uint)tile[(nb + 7) * LD + d] << 16);
        }
        *reinterpret_cast<uint4*>(outp + (size_t)d * VT_LD + c * 8) = make_uint4(w0, w1, w2, w3);
    }
}

// ---------------- fused attention: block = (b,h), 8 waves, K/VT staged ONCE ----------------
__global__ __launch_bounds__(512) void k_attn(const ushort* __restrict__ qkv, const ushort* __restrict__ vt,
                                              const ushort* __restrict__ biash, ushort* __restrict__ out) {
    constexpr int KLD = 72;
    extern __shared__ ushort sm[];
    ushort* kp  = sm;
    ushort* vts = sm + NPAD * KLD;
    ushort* ps  = vts + 64 * VT_LD;
    const int tid = threadIdx.x, wid = tid >> 6, lane = tid & 63;
    const int fr = lane & 15, fg = lane >> 4;
    const int bh = blockIdx.x;
    const int b = bh / NH, h = bh % NH;
    const size_t qb = (size_t)(b * NTOK) * 2304;

    for (int t = tid; t < NPAD * 8; t += 512) {
        const int row = t >> 3, seg = t & 7;
        uint4 val = make_uint4(0u, 0u, 0u, 0u);
        if (row < NTOK) val = *reinterpret_cast<const uint4*>(qkv + qb + (size_t)row * 2304 + 768 + h * 64 + seg * 8);
        *reinterpret_cast<uint4*>(kp + row * KLD + seg * 8) = val;
    }
    const ushort* vtg = vt + (size_t)bh * (64 * VT_LD);
    for (int t = tid; t < 64 * 29; t += 512)
        *reinterpret_cast<uint4*>(vts + t * 8) = *reinterpret_cast<const uint4*>(vtg + t * 8);
    __syncthreads();

    ushort* pw = ps + wid * 16 * VT_LD;

    for (int s = wid; s < 13; s += 8) {
        const int q0 = s * 16;
        f16x8 qf[2];
        {
            int row = q0 + fr;
            row = row < NTOK ? row : NTOK - 1;
            const ushort* qp = qkv + qb + (size_t)row * 2304 + h * 64 + fg * 8;
            qf[0] = *reinterpret_cast<const f16x8*>(qp);
            qf[1] = *reinterpret_cast<const f16x8*>(qp + 32);
        }
        f32x4 sacc[14] = {};
#pragma unroll
        for (int j = 0; j < 14; ++j) {
#pragma unroll
            for (int kh = 0; kh < 2; ++kh) {
                f16x8 kf = *reinterpret_cast<const f16x8*>(kp + (j * 16 + fr) * KLD + kh * 32 + fg * 8);
                sacc[j] = __builtin_amdgcn_mfma_f32_16x16x32_f16(qf[kh], kf, sacc[j], 0, 0, 0);
            }
        }
        float rs4[4];
#pragma unroll
        for (int r = 0; r < 4; ++r) {
            const int qrow_l = fg * 4 + r;
            int qrow = q0 + qrow_l;
            qrow = qrow < NTOK ? qrow : NTOK - 1;
            const ushort* bp16 = biash + (((size_t)(h * NPAD + qrow) * 16 + fr) << 4);
            f16x8 bv0 = *reinterpret_cast<const f16x8*>(bp16);
            f16x8 bv1 = *reinterpret_cast<const f16x8*>(bp16 + 8);
            float mx = -1e30f;
#pragma unroll
            for (int j = 0; j < 14; ++j) {
                const float bj = (float)(j < 8 ? bv0[j] : bv1[j - 8]);
                float v = sacc[j][r] + bj;
                sacc[j][r] = v;
                mx = fmaxf(mx, v);
            }
            mx = fmaxf(mx, __shfl_xor(mx, 1));
            mx = fmaxf(mx, __shfl_xor(mx, 2));
            mx = fmaxf(mx, __shfl_xor(mx, 4));
            mx = fmaxf(mx, __shfl_xor(mx, 8));
            float sum = 0.f;
            ushort* prow = pw + qrow_l * VT_LD;
#pragma unroll
            for (int j = 0; j < 14; ++j) {
                float p = __expf(sacc[j][r] - mx);
                sum += p;
                prow[j * 16 + fr] = f2h_bits(p);
            }
            sum += __shfl_xor(sum, 1);
            sum += __shfl_xor(sum, 2);
            sum += __shfl_xor(sum, 4);
            sum += __shfl_xor(sum, 8);
            rs4[r] = sum;
        }
        f32x4 o[4] = {};
#pragma unroll
        for (int kc = 0; kc < 7; ++kc) {
            f16x8 af = *reinterpret_cast<const f16x8*>(pw + fr * VT_LD + kc * 32 + fg * 8);
#pragma unroll
            for (int dt = 0; dt < 4; ++dt) {
                f16x8 bv = *reinterpret_cast<const f16x8*>(vts + (dt * 16 + fr) * VT_LD + kc * 32 + fg * 8);
                o[dt] = __builtin_amdgcn_mfma_f32_16x16x32_f16(af, bv, o[dt], 0, 0, 0);
            }
        }
#pragma unroll
        for (int dt = 0; dt < 4; ++dt) {
#pragma unroll
            for (int r = 0; r < 4; ++r) {
                const int qrow = q0 + fg * 4 + r;
                if (qrow < NTOK) {
                    const float val = o[dt][r] / rs4[r];
                    out[(size_t)(b * NTOK + qrow) * DIM + h * 64 + dt * 16 + fr] = f2h_bits(val);
                }
            }
        }
    }
}

extern "C" void kernel_launch(void* const* d_in, const int* in_sizes, int n_in,
                              void* d_out, int out_size, void* d_ws, size_t ws_size,
                              hipStream_t stream) {
    const float* x         = (const float*)d_in[0];
    const float* Wqkv      = (const float*)d_in[1];
    const float* q_bias    = (const float*)d_in[2];
    const float* v_bias    = (const float*)d_in[3];
    const float* rel_table = (const float*)d_in[4];
    const float* Wproj     = (const float*)d_in[5];
    const float* bproj     = (const float*)d_in[6];
    const int*   rel_index = (const int*)d_in[7];
    float* out = (float*)d_out;

    char* p = (char*)d_ws;
    auto alloc = [&](size_t bytes) { char* r = p; p += (bytes + 255) & ~(size_t)255; return r; };
    ushort* xb     = (ushort*)alloc((size_t)M_TOK * DIM * 2);
    ushort* wqkvb  = (ushort*)alloc((size_t)2304 * 768 * 2);
    ushort* wprojb = (ushort*)alloc((size_t)768 * 768 * 2);
    ushort* qkvb   = (ushort*)alloc((size_t)M_TOK * 2304 * 2);
    ushort* vtb    = (ushort*)alloc((size_t)NB * NH * 64 * VT_LD * 2);
    ushort* biasb  = (ushort*)alloc((size_t)NH * NPAD * 256 * 2);
    ushort* aob    = (ushort*)alloc((size_t)M_TOK * DIM * 2);

    (void)hipFuncSetAttribute((const void*)k_qkv8, hipFuncAttributeMaxDynamicSharedMemorySize, 131072);
    constexpr int ATTN_LDS = (NPAD * 72 + 64 * VT_LD + 8 * 16 * VT_LD) * 2;  // 121344 B
    (void)hipFuncSetAttribute((const void*)k_attn, hipFuncAttributeMaxDynamicSharedMemorySize, ATTN_LDS);

    int n4 = M_TOK * DIM / 4;
    k_cvt<<<(n4 + 255) / 256, 256, 0, stream>>>(x, xb, n4);
    n4 = 2304 * 768 / 4;
    k_cvt<<<(n4 + 255) / 256, 256, 0, stream>>>(Wqkv, wqkvb, n4);
    n4 = 768 * 768 / 4;
    k_cvt<<<(n4 + 255) / 256, 256, 0, stream>>>(Wproj, wprojb, n4);
    int nbias = NH * NPAD * 256;
    k_bias<<<(nbias + 255) / 256, 256, 0, stream>>>(rel_table, rel_index, biasb);

    k_qkv8<<<dim3(2304 / 256, (M_TOK + 255) / 256), 512, 131072, stream>>>(
        xb, wqkvb, q_bias, v_bias, qkvb);
    k_vt<<<NB * NH, 256, 0, stream>>>(qkvb, vtb);
    k_attn<<<dim3(NB * NH), 512, ATTN_LDS, stream>>>(qkvb, vtb, biasb, aob);
    k_gemm<1><<<dim3(768 / 128, (M_TOK + 127) / 128), 256, 0, stream>>>(
        aob, wprojb, M_TOK, 768, 768, nullptr, nullptr, bproj, nullptr, out);
}

// Round 7
// 166.037 us; speedup vs baseline: 1.4239x; 1.1481x over previous
//
#include <hip/hip_runtime.h>

typedef _Float16 f16_t;
typedef f16_t f16x8 __attribute__((ext_vector_type(8)));
typedef float f32x4 __attribute__((ext_vector_type(4)));

#define DEVI __device__ __forceinline__

constexpr int NB    = 64;
constexpr int NTOK  = 197;
constexpr int NH    = 12;
constexpr int DIM   = 768;
constexpr int M_TOK = NB * NTOK;   // 12608
constexpr int NPAD  = 224;         // 14*16 padded token count
constexpr float SCALE = 0.125f;    // 64^-0.5

// attn LDS geometry (all strides chosen for measured-conflict-free patterns)
constexpr int KP_SZ  = 2 * NPAD * 32;   // [kh][224][32] = 14336 ushorts
constexpr int VTS_SZ = 7 * 64 * 32;     // [kc][64][32]  = 14336 ushorts
constexpr int P_LD   = 228;             // P row stride: 4*114 = 456 =  8 mod 32 words
constexpr int PW_SZ  = 16 * P_LD;       // 3648 ushorts per wave
constexpr int ATTN_LDS = (KP_SZ + VTS_SZ + 8 * PW_SZ) * 2;  // 115712 B

DEVI ushort f2h_bits(float f) { _Float16 h = (_Float16)f; return __builtin_bit_cast(ushort, h); }

DEVI void gload16(const void* g, void* l) {
    __builtin_amdgcn_global_load_lds((const __attribute__((address_space(1))) void*)g,
                                     (__attribute__((address_space(3))) void*)l, 16, 0, 0);
}

// ---------------- fp32 -> fp16 convert ----------------
__global__ __launch_bounds__(256) void k_cvt(const float* __restrict__ in, ushort* __restrict__ out, int n4) {
    int i = blockIdx.x * 256 + threadIdx.x;
    if (i >= n4) return;
    float4 v = reinterpret_cast<const float4*>(in)[i];
    ushort4 o;
    o.x = f2h_bits(v.x); o.y = f2h_bits(v.y); o.z = f2h_bits(v.z); o.w = f2h_bits(v.w);
    reinterpret_cast<ushort4*>(out)[i] = o;
}

// ---------------- rel-pos bias gather, f16, FRAGMENT-ORDERED [h][qrow][fr][16] ----------------
__global__ __launch_bounds__(256) void k_bias(const float* __restrict__ rel_table,
                                              const int* __restrict__ rel_index,
                                              ushort* __restrict__ biash) {
    int idx = blockIdx.x * 256 + threadIdx.x;
    if (idx >= NH * NPAD * 256) return;
    const int j  = idx & 15;
    const int fr = (idx >> 4) & 15;
    const int i  = (idx >> 8) % NPAD;
    const int h  = (idx >> 8) / NPAD;
    const int col = j * 16 + fr;
    float v = -30000.f;
    if (i < NTOK && col < NTOK && j < 14) v = rel_table[rel_index[i * NTOK + col] * NH + h];
    biash[idx] = f2h_bits(v);
}

// ================= QKV GEMM: 256x256, BK=64, 8-phase counted-vmcnt schedule =================
__global__ __launch_bounds__(512, 2) void k_qkv8(const ushort* __restrict__ A, const ushort* __restrict__ BT,
                                                 const float* __restrict__ b_q, const float* __restrict__ b_v,
                                                 ushort* __restrict__ outp) {
    constexpr int M = M_TOK, N = 2304, K = 768, nt = K / 64;  // nt = 12 (even)
    extern __shared__ ushort lds[];           // 65536 ushorts = 128 KiB
    ushort* ldsA = lds;
    ushort* ldsB = lds + 32768;
    const int tid = threadIdx.x, wid = tid >> 6, lane = tid & 63;
    const int wm = wid >> 2, wn = wid & 3;
    const int fr = lane & 15, fg = lane >> 4;
    const int m0 = blockIdx.y * 256, n0 = blockIdx.x * 256;

    const int srow = tid >> 2;
    const int sc = ((tid & 3) ^ ((tid >> 3) & 3)) * 8;
    int ra0 = m0 + srow;       ra0 = ra0 < M ? ra0 : M - 1;
    int ra1 = m0 + srow + 128; ra1 = ra1 < M ? ra1 : M - 1;
    const ushort* pA0 = A + (size_t)ra0 * K + sc;
    const ushort* pA1 = A + (size_t)ra1 * K + sc;
    const ushort* pB0 = BT + (size_t)(n0 + srow) * K + sc;
    const ushort* pB1 = BT + (size_t)(n0 + srow + 128) * K + sc;
    const int dstt = tid * 8;

    int aoff[8], boff[4];
#pragma unroll
    for (int mi = 0; mi < 8; ++mi) {
        const int r = wm * 128 + mi * 16 + fr;
        aoff[mi] = r * 32 + ((fg ^ ((r >> 1) & 3)) * 8);
    }
#pragma unroll
    for (int j = 0; j < 4; ++j) {
        const int c = wn * 64 + j * 16 + fr;
        boff[j] = c * 32 + ((fg ^ ((c >> 1) & 3)) * 8);
    }

    f32x4 acc[8][4] = {};
    f16x8 av[8];

    auto STAGE = [&](int T, int isA, int k) {
        const int Tw = T >= nt ? T - nt : T;
        const size_t so = (size_t)(Tw * 64 + k * 32);
        const int db = (T & 1) * 16384 + k * 8192 + dstt;
        if (isA) { gload16(pA0 + so, ldsA + db); gload16(pA1 + so, ldsA + db + 4096); }
        else     { gload16(pB0 + so, ldsB + db); gload16(pB1 + so, ldsB + db + 4096); }
    };

#define LDA8(B_, KS_) { _Pragma("unroll") for (int mi = 0; mi < 8; ++mi) \
        av[mi] = *(const f16x8*)(ldsA + (B_) * 16384 + (KS_) * 8192 + aoff[mi]); }

#define PHASE(B_, KS_, NH_, LA_, ST_T, ST_A, ST_K, GATE_) { \
        if (LA_) LDA8(B_, KS_); \
        f16x8 bv0 = *(const f16x8*)(ldsB + (B_) * 16384 + (KS_) * 8192 + boff[(NH_) * 2]); \
        f16x8 bv1 = *(const f16x8*)(ldsB + (B_) * 16384 + (KS_) * 8192 + boff[(NH_) * 2 + 1]); \
        STAGE(ST_T, ST_A, ST_K); \
        __builtin_amdgcn_s_barrier(); \
        __builtin_amdgcn_s_setprio(1); \
        _Pragma("unroll") for (int mi = 0; mi < 8; ++mi) { \
            acc[mi][(NH_) * 2]     = __builtin_amdgcn_mfma_f32_16x16x32_f16(av[mi], bv0, acc[mi][(NH_) * 2], 0, 0, 0); \
            acc[mi][(NH_) * 2 + 1] = __builtin_amdgcn_mfma_f32_16x16x32_f16(av[mi], bv1, acc[mi][(NH_) * 2 + 1], 0, 0, 0); } \
        __builtin_amdgcn_s_setprio(0); \
        asm volatile("s_waitcnt lgkmcnt(0)" ::: "memory"); \
        __builtin_amdgcn_sched_barrier(0); \
        if (GATE_) { asm volatile("s_waitcnt vmcnt(4)" ::: "memory"); __builtin_amdgcn_sched_barrier(0); } \
        __builtin_amdgcn_s_barrier(); }

    STAGE(0, 1, 0); STAGE(0, 0, 0); STAGE(0, 1, 1); STAGE(0, 0, 1);
    STAGE(1, 1, 0); STAGE(1, 0, 0);
    asm volatile("s_waitcnt vmcnt(4)" ::: "memory");
    __builtin_amdgcn_sched_barrier(0);
    __builtin_amdgcn_s_barrier();

    for (int i = 0; i < nt / 2; ++i) {
        const int t0 = 2 * i;
        PHASE(0, 0, 0, 1, t0 + 1, 1, 1, 0)
        PHASE(0, 0, 1, 0, t0 + 1, 0, 1, 0)
        PHASE(0, 1, 0, 1, t0 + 2, 1, 0, 0)
        PHASE(0, 1, 1, 0, t0 + 2, 0, 0, 1)
        PHASE(1, 0, 0, 1, t0 + 2, 1, 1, 0)
        PHASE(1, 0, 1, 0, t0 + 2, 0, 1, 0)
        PHASE(1, 1, 0, 1, t0 + 3, 1, 0, 0)
        PHASE(1, 1, 1, 0, t0 + 3, 0, 0, 1)
    }
#undef PHASE
#undef LDA8

    asm volatile("s_waitcnt vmcnt(0) lgkmcnt(0)" ::: "memory");
    __builtin_amdgcn_sched_barrier(0);
    __builtin_amdgcn_s_barrier();

    // epilogue: bias -> f16 -> wave-private LDS -> coalesced 16B stores
    ushort* ws = lds + wid * 8192;
#pragma unroll
    for (int ni = 0; ni < 4; ++ni) {
        const int col = n0 + wn * 64 + ni * 16 + fr;
        float addv, mul;
        if (col < 768)       { addv = b_q[col]; mul = SCALE; }
        else if (col < 1536) { addv = 0.f; mul = 1.f; }
        else                 { addv = b_v[col - 1536]; mul = 1.f; }
#pragma unroll
        for (int mi = 0; mi < 8; ++mi)
#pragma unroll
            for (int r = 0; r < 4; ++r)
                ws[(mi * 16 + fg * 4 + r) * 64 + ni * 16 + fr] = f2h_bits((acc[mi][ni][r] + addv) * mul);
    }
    __syncthreads();
#pragma unroll
    for (int it = 0; it < 16; ++it) {
        const int g = it * 64 + lane;
        const int r = g >> 3, seg = g & 7;
        const int row = m0 + wm * 128 + r;
        uint4 v = *(const uint4*)(ws + r * 64 + seg * 8);
        if (row < M) *(uint4*)(outp + (size_t)row * N + n0 + wn * 64 + seg * 8) = v;
    }
}

// ---------------- 128x128 BT GEMM, BK=32, dbuf, XOR-swizzled (proj) ----------------
template<int EPI>
__global__ __launch_bounds__(256) void k_gemm(const ushort* __restrict__ A, const ushort* __restrict__ BT,
                                              int M, int N, int K,
                                              const float* __restrict__ b_q, const float* __restrict__ b_v,
                                              const float* __restrict__ b_p,
                                              ushort* __restrict__ out_h, float* __restrict__ out_f) {
    __shared__ __align__(16) ushort lds[2][8192];
    const int tid = threadIdx.x, wid = tid >> 6, lane = tid & 63;
    const int wm = wid >> 1, wn = wid & 1;
    const int fr = lane & 15, fg = lane >> 4;
    const int m0 = blockIdx.y * 128, n0 = blockIdx.x * 128;

    int rA[2], rB[2], cs[2], dst[2];
#pragma unroll
    for (int i = 0; i < 2; ++i) {
        const int g = (wid * 2 + i) * 64 + lane;
        const int row = g >> 2, sp = g & 3;
        cs[i]  = (sp ^ ((row >> 1) & 3)) * 8;
        dst[i] = (wid * 2 + i) * 512;
        const int ra = m0 + row;
        rA[i] = ra < M ? ra : M - 1;
        rB[i] = n0 + row;
    }

    f32x4 acc[4][4] = {};
    const int nt = K / 32;

    auto stage = [&](int t, int buf) {
#pragma unroll
        for (int i = 0; i < 2; ++i)
            gload16(A + (size_t)rA[i] * K + t * 32 + cs[i], &lds[buf][dst[i]]);
#pragma unroll
        for (int i = 0; i < 2; ++i)
            gload16(BT + (size_t)rB[i] * K + t * 32 + cs[i], &lds[buf][4096 + dst[i]]);
    };

    stage(0, 0);
    __syncthreads();
    for (int t = 0; t < nt; ++t) {
        const int cur = t & 1;
        if (t + 1 < nt) stage(t + 1, cur ^ 1);
        const ushort* As = lds[cur];
        const ushort* Bs = lds[cur] + 4096;
        f16x8 af[4], bf[4];
#pragma unroll
        for (int i = 0; i < 4; ++i) {
            const int r = wm * 64 + i * 16 + fr;
            af[i] = *(const f16x8*)(As + r * 32 + ((fg ^ ((r >> 1) & 3)) * 8));
        }
#pragma unroll
        for (int i = 0; i < 4; ++i) {
            const int c = wn * 64 + i * 16 + fr;
            bf[i] = *(const f16x8*)(Bs + c * 32 + ((fg ^ ((c >> 1) & 3)) * 8));
        }
#pragma unroll
        for (int mi = 0; mi < 4; ++mi)
#pragma unroll
            for (int ni = 0; ni < 4; ++ni)
                acc[mi][ni] = __builtin_amdgcn_mfma_f32_16x16x32_f16(af[mi], bf[ni], acc[mi][ni], 0, 0, 0);
        __syncthreads();
    }

#pragma unroll
    for (int ni = 0; ni < 4; ++ni) {
        const int col = n0 + wn * 64 + ni * 16 + fr;
        float addv = 0.f, mul = 1.f;
        if (EPI == 0) {
            if (col < 768)       { addv = b_q[col]; mul = SCALE; }
            else if (col < 1536) { addv = 0.f; }
            else                 { addv = b_v[col - 1536]; }
        } else {
            addv = b_p[col];
        }
#pragma unroll
        for (int mi = 0; mi < 4; ++mi) {
#pragma unroll
            for (int r = 0; r < 4; ++r) {
                const int row = m0 + wm * 64 + mi * 16 + fg * 4 + r;
                if (row < M) {
                    float v = (acc[mi][ni][r] + addv) * mul;
                    if (EPI == 0) out_h[(size_t)row * N + col] = f2h_bits(v);
                    else          out_f[(size_t)row * N + col] = v;
                }
            }
        }
    }
}

// ================ fused attention v3: block=(b,h), 8 waves, conflict-free LDS ================
// kp  [kh=2][224][32] XOR-swizzled  (GEMM's measured-0-conflict read pattern)
// vts [kc=7][64][32]  XOR-swizzled, built by in-kernel V transpose (k_vt fused; temp tile in ps)
// ps  [wave][16][228]  P buffer; stride 228: write banks = fg*{0,8,16,24}+fr/2 -> 2-way (free)
__global__ __launch_bounds__(512) void k_attn(const ushort* __restrict__ qkv,
                                              const ushort* __restrict__ biash, ushort* __restrict__ out) {
    extern __shared__ ushort sm[];
    ushort* kp  = sm;                    // 14336
    ushort* vts = sm + KP_SZ;            // 14336
    ushort* ps  = sm + KP_SZ + VTS_SZ;   // 29184
    const int tid = threadIdx.x, wid = tid >> 6, lane = tid & 63;
    const int fr = lane & 15, fg = lane >> 4;
    const int bh = blockIdx.x;
    const int b = bh / NH, h = bh % NH;
    const size_t qb = (size_t)(b * NTOK) * 2304;
    const int swz8 = (fg ^ ((fr >> 1) & 3)) * 8;   // lane-constant read swizzle (row>>1&3 == fr>>1&3)

    // K -> kp chunked+swizzled; V -> temp tile [224][72] in ps region
    ushort* vtile = ps;
    for (int t = tid; t < NPAD * 8; t += 512) {
        const int row = t >> 3, seg = t & 7;
        uint4 kv = make_uint4(0u, 0u, 0u, 0u), vv = make_uint4(0u, 0u, 0u, 0u);
        if (row < NTOK) {
            const ushort* src = qkv + qb + (size_t)row * 2304 + 768 + h * 64;
            kv = *reinterpret_cast<const uint4*>(src + seg * 8);
            vv = *reinterpret_cast<const uint4*>(src + 768 + seg * 8);
        }
        const int pcg = (seg & 3) ^ ((row >> 1) & 3);
        *reinterpret_cast<uint4*>(kp + (seg >> 2) * (NPAD * 32) + row * 32 + pcg * 8) = kv;
        *reinterpret_cast<uint4*>(vtile + row * 72 + seg * 8) = vv;
    }
    __syncthreads();
    // transpose vtile -> vts [kc][64][32] (physical col-group pcg holds logical group pcg^((d>>1)&3))
    for (int o = tid; o < 7 * 64 * 4; o += 512) {
        const int kc = o >> 8, rem = o & 255, d = rem >> 2, pcg = rem & 3;
        const int k0 = kc * 32 + (pcg ^ ((d >> 1) & 3)) * 8;
        ushort w[8];
#pragma unroll
        for (int e = 0; e < 8; ++e) w[e] = vtile[(k0 + e) * 72 + d];
        uint4 val;
        val.x = (uint)w[0] | ((uint)w[1] << 16);
        val.y = (uint)w[2] | ((uint)w[3] << 16);
        val.z = (uint)w[4] | ((uint)w[5] << 16);
        val.w = (uint)w[6] | ((uint)w[7] << 16);
        *reinterpret_cast<uint4*>(vts + kc * 2048 + d * 32 + pcg * 8) = val;
    }
    __syncthreads();   // also guards vtile (ps) reuse as P below

    ushort* pw = ps + wid * PW_SZ;

    for (int s = wid; s < 13; s += 8) {
        const int q0 = s * 16;
        f16x8 qf[2];
        {
            int row = q0 + fr;
            row = row < NTOK ? row : NTOK - 1;
            const ushort* qp = qkv + qb + (size_t)row * 2304 + h * 64 + fg * 8;
            qf[0] = *reinterpret_cast<const f16x8*>(qp);
            qf[1] = *reinterpret_cast<const f16x8*>(qp + 32);
        }
        // S = Q K^T
        f32x4 sacc[14] = {};
#pragma unroll
        for (int j = 0; j < 14; ++j) {
#pragma unroll
            for (int kh = 0; kh < 2; ++kh) {
                f16x8 kf = *reinterpret_cast<const f16x8*>(kp + kh * (NPAD * 32) + (j * 16 + fr) * 32 + swz8);
                sacc[j] = __builtin_amdgcn_mfma_f32_16x16x32_f16(qf[kh], kf, sacc[j], 0, 0, 0);
            }
        }
        // bias + masked softmax; P -> wave-private LDS (stride 228)
        float rs4[4];
#pragma unroll
        for (int r = 0; r < 4; ++r) {
            const int qrow_l = fg * 4 + r;
            int qrow = q0 + qrow_l;
            qrow = qrow < NTOK ? qrow : NTOK - 1;
            const ushort* bp16 = biash + (((size_t)(h * NPAD + qrow) * 16 + fr) << 4);
            f16x8 bv0 = *reinterpret_cast<const f16x8*>(bp16);
            f16x8 bv1 = *reinterpret_cast<const f16x8*>(bp16 + 8);
            float mx = -1e30f;
#pragma unroll
            for (int j = 0; j < 14; ++j) {
                const float bj = (float)(j < 8 ? bv0[j] : bv1[j - 8]);
                float v = sacc[j][r] + bj;
                sacc[j][r] = v;
                mx = fmaxf(mx, v);
            }
            mx = fmaxf(mx, __shfl_xor(mx, 1));
            mx = fmaxf(mx, __shfl_xor(mx, 2));
            mx = fmaxf(mx, __shfl_xor(mx, 4));
            mx = fmaxf(mx, __shfl_xor(mx, 8));
            float sum = 0.f;
            ushort* prow = pw + qrow_l * P_LD;
#pragma unroll
            for (int j = 0; j < 14; ++j) {
                float p = __expf(sacc[j][r] - mx);
                sum += p;
                prow[j * 16 + fr] = f2h_bits(p);
            }
            sum += __shfl_xor(sum, 1);
            sum += __shfl_xor(sum, 2);
            sum += __shfl_xor(sum, 4);
            sum += __shfl_xor(sum, 8);
            rs4[r] = sum;
        }
        // O = P V
        f32x4 o[4] = {};
#pragma unroll
        for (int kc = 0; kc < 7; ++kc) {
            f16x8 af = *reinterpret_cast<const f16x8*>(pw + fr * P_LD + kc * 32 + fg * 8);
#pragma unroll
            for (int dt = 0; dt < 4; ++dt) {
                f16x8 bv = *reinterpret_cast<const f16x8*>(vts + kc * 2048 + (dt * 16 + fr) * 32 + swz8);
                o[dt] = __builtin_amdgcn_mfma_f32_16x16x32_f16(af, bv, o[dt], 0, 0, 0);
            }
        }
#pragma unroll
        for (int dt = 0; dt < 4; ++dt) {
#pragma unroll
            for (int r = 0; r < 4; ++r) {
                const int qrow = q0 + fg * 4 + r;
                if (qrow < NTOK) {
                    const float val = o[dt][r] / rs4[r];
                    out[(size_t)(b * NTOK + qrow) * DIM + h * 64 + dt * 16 + fr] = f2h_bits(val);
                }
            }
        }
    }
}

extern "C" void kernel_launch(void* const* d_in, const int* in_sizes, int n_in,
                              void* d_out, int out_size, void* d_ws, size_t ws_size,
                              hipStream_t stream) {
    const float* x         = (const float*)d_in[0];
    const float* Wqkv      = (const float*)d_in[1];
    const float* q_bias    = (const float*)d_in[2];
    const float* v_bias    = (const float*)d_in[3];
    const float* rel_table = (const float*)d_in[4];
    const float* Wproj     = (const float*)d_in[5];
    const float* bproj     = (const float*)d_in[6];
    const int*   rel_index = (const int*)d_in[7];
    float* out = (float*)d_out;

    char* p = (char*)d_ws;
    auto alloc = [&](size_t bytes) { char* r = p; p += (bytes + 255) & ~(size_t)255; return r; };
    ushort* xb     = (ushort*)alloc((size_t)M_TOK * DIM * 2);
    ushort* wqkvb  = (ushort*)alloc((size_t)2304 * 768 * 2);
    ushort* wprojb = (ushort*)alloc((size_t)768 * 768 * 2);
    ushort* qkvb   = (ushort*)alloc((size_t)M_TOK * 2304 * 2);
    ushort* biasb  = (ushort*)alloc((size_t)NH * NPAD * 256 * 2);
    ushort* aob    = (ushort*)alloc((size_t)M_TOK * DIM * 2);

    (void)hipFuncSetAttribute((const void*)k_qkv8, hipFuncAttributeMaxDynamicSharedMemorySize, 131072);
    (void)hipFuncSetAttribute((const void*)k_attn, hipFuncAttributeMaxDynamicSharedMemorySize, ATTN_LDS);

    int n4 = M_TOK * DIM / 4;
    k_cvt<<<(n4 + 255) / 256, 256, 0, stream>>>(x, xb, n4);
    n4 = 2304 * 768 / 4;
    k_cvt<<<(n4 + 255) / 256, 256, 0, stream>>>(Wqkv, wqkvb, n4);
    n4 = 768 * 768 / 4;
    k_cvt<<<(n4 + 255) / 256, 256, 0, stream>>>(Wproj, wprojb, n4);
    int nbias = NH * NPAD * 256;
    k_bias<<<(nbias + 255) / 256, 256, 0, stream>>>(rel_table, rel_index, biasb);

    k_qkv8<<<dim3(2304 / 256, (M_TOK + 255) / 256), 512, 131072, stream>>>(
        xb, wqkvb, q_bias, v_bias, qkvb);
    k_attn<<<dim3(NB * NH), 512, ATTN_LDS, stream>>>(qkvb, biasb, aob);
    k_gemm<1><<<dim3(768 / 128, (M_TOK + 127) / 128), 256, 0, stream>>>(
        aob, wprojb, M_TOK, 768, 768, nullptr, nullptr, bproj, nullptr, out);
}

// Round 8
// 154.303 us; speedup vs baseline: 1.5322x; 1.0760x over previous
//
#include <hip/hip_runtime.h>

typedef _Float16 f16_t;
typedef f16_t f16x8 __attribute__((ext_vector_type(8)));
typedef float f32x4 __attribute__((ext_vector_type(4)));

#define DEVI __device__ __forceinline__

constexpr int NB    = 64;
constexpr int NTOK  = 197;
constexpr int NH    = 12;
constexpr int DIM   = 768;
constexpr int M_TOK = NB * NTOK;   // 12608
constexpr int NPAD  = 224;         // 14*16 padded token count
constexpr float SCALE = 0.125f;    // 64^-0.5

// attn LDS geometry
constexpr int KP_SZ  = 2 * NPAD * 32;
constexpr int VTS_SZ = 7 * 64 * 32;
constexpr int P_LD   = 228;
constexpr int PW_SZ  = 16 * P_LD;
constexpr int ATTN_LDS = (KP_SZ + VTS_SZ + 8 * PW_SZ) * 2;  // 115712 B

DEVI ushort f2h_bits(float f) { _Float16 h = (_Float16)f; return __builtin_bit_cast(ushort, h); }

DEVI void gload16(const void* g, void* l) {
    __builtin_amdgcn_global_load_lds((const __attribute__((address_space(1))) void*)g,
                                     (__attribute__((address_space(3))) void*)l, 16, 0, 0);
}

// bijective XCD swizzle (m204): orig dispatch id -> tile id, valid for any nwg
DEVI int xcd_swz(int orig, int nwg) {
    const int q = nwg >> 3, r = nwg & 7;
    const int xcd = orig & 7, idx = orig >> 3;
    return (xcd < r ? xcd * (q + 1) : r * (q + 1) + (xcd - r) * q) + idx;
}

// ---------------- fused fp32 -> fp16 convert (x | Wqkv | Wproj in one launch) ----------------
__global__ __launch_bounds__(256) void k_cvt3(const float* __restrict__ s0, ushort* __restrict__ d0, int n0,
                                              const float* __restrict__ s1, ushort* __restrict__ d1, int n1,
                                              const float* __restrict__ s2, ushort* __restrict__ d2, int n2) {
    int i = blockIdx.x * 256 + threadIdx.x;
    const float* s; ushort* d;
    if (i < n0)           { s = s0; d = d0; }
    else if (i < n0 + n1) { i -= n0; s = s1; d = d1; }
    else                  { i -= n0 + n1; if (i >= n2) return; s = s2; d = d2; }
    float4 v = reinterpret_cast<const float4*>(s)[i];
    ushort4 o;
    o.x = f2h_bits(v.x); o.y = f2h_bits(v.y); o.z = f2h_bits(v.z); o.w = f2h_bits(v.w);
    reinterpret_cast<ushort4*>(d)[i] = o;
}

// ---------------- rel-pos bias gather, f16, FRAGMENT-ORDERED [h][qrow][fr][16] ----------------
__global__ __launch_bounds__(256) void k_bias(const float* __restrict__ rel_table,
                                              const int* __restrict__ rel_index,
                                              ushort* __restrict__ biash) {
    int idx = blockIdx.x * 256 + threadIdx.x;
    if (idx >= NH * NPAD * 256) return;
    const int j  = idx & 15;
    const int fr = (idx >> 4) & 15;
    const int i  = (idx >> 8) % NPAD;
    const int h  = (idx >> 8) / NPAD;
    const int col = j * 16 + fr;
    float v = -30000.f;
    if (i < NTOK && col < NTOK && j < 14) v = rel_table[rel_index[i * NTOK + col] * NH + h];
    biash[idx] = f2h_bits(v);
}

// ================= QKV GEMM: 256x256, BK=64, 8-phase counted-vmcnt + XCD swizzle =================
__global__ __launch_bounds__(512, 2) void k_qkv8(const ushort* __restrict__ A, const ushort* __restrict__ BT,
                                                 const float* __restrict__ b_q, const float* __restrict__ b_v,
                                                 ushort* __restrict__ outp) {
    constexpr int M = M_TOK, N = 2304, K = 768, nt = K / 64;  // nt = 12 (even)
    constexpr int NWG = (N / 256) * 50;                       // 9 * 50 = 450
    extern __shared__ ushort lds[];
    ushort* ldsA = lds;
    ushort* ldsB = lds + 32768;
    const int tid = threadIdx.x, wid = tid >> 6, lane = tid & 63;
    const int wm = wid >> 2, wn = wid & 3;
    const int fr = lane & 15, fg = lane >> 4;
    // XCD swizzle: consecutive dispatch ids -> same XCD chunk, n-major within chunk
    const int bid = xcd_swz(blockIdx.y * (N / 256) + blockIdx.x, NWG);
    const int m0 = (bid / (N / 256)) * 256, n0 = (bid % (N / 256)) * 256;

    const int srow = tid >> 2;
    const int sc = ((tid & 3) ^ ((tid >> 3) & 3)) * 8;
    int ra0 = m0 + srow;       ra0 = ra0 < M ? ra0 : M - 1;
    int ra1 = m0 + srow + 128; ra1 = ra1 < M ? ra1 : M - 1;
    const ushort* pA0 = A + (size_t)ra0 * K + sc;
    const ushort* pA1 = A + (size_t)ra1 * K + sc;
    const ushort* pB0 = BT + (size_t)(n0 + srow) * K + sc;
    const ushort* pB1 = BT + (size_t)(n0 + srow + 128) * K + sc;
    const int dstt = tid * 8;

    int aoff[8], boff[4];
#pragma unroll
    for (int mi = 0; mi < 8; ++mi) {
        const int r = wm * 128 + mi * 16 + fr;
        aoff[mi] = r * 32 + ((fg ^ ((r >> 1) & 3)) * 8);
    }
#pragma unroll
    for (int j = 0; j < 4; ++j) {
        const int c = wn * 64 + j * 16 + fr;
        boff[j] = c * 32 + ((fg ^ ((c >> 1) & 3)) * 8);
    }

    f32x4 acc[8][4] = {};
    f16x8 av[8];

    auto STAGE = [&](int T, int isA, int k) {
        const int Tw = T >= nt ? T - nt : T;
        const size_t so = (size_t)(Tw * 64 + k * 32);
        const int db = (T & 1) * 16384 + k * 8192 + dstt;
        if (isA) { gload16(pA0 + so, ldsA + db); gload16(pA1 + so, ldsA + db + 4096); }
        else     { gload16(pB0 + so, ldsB + db); gload16(pB1 + so, ldsB + db + 4096); }
    };

#define LDA8(B_, KS_) { _Pragma("unroll") for (int mi = 0; mi < 8; ++mi) \
        av[mi] = *(const f16x8*)(ldsA + (B_) * 16384 + (KS_) * 8192 + aoff[mi]); }

#define PHASE(B_, KS_, NH_, LA_, ST_T, ST_A, ST_K, GATE_) { \
        if (LA_) LDA8(B_, KS_); \
        f16x8 bv0 = *(const f16x8*)(ldsB + (B_) * 16384 + (KS_) * 8192 + boff[(NH_) * 2]); \
        f16x8 bv1 = *(const f16x8*)(ldsB + (B_) * 16384 + (KS_) * 8192 + boff[(NH_) * 2 + 1]); \
        STAGE(ST_T, ST_A, ST_K); \
        __builtin_amdgcn_s_barrier(); \
        __builtin_amdgcn_s_setprio(1); \
        _Pragma("unroll") for (int mi = 0; mi < 8; ++mi) { \
            acc[mi][(NH_) * 2]     = __builtin_amdgcn_mfma_f32_16x16x32_f16(av[mi], bv0, acc[mi][(NH_) * 2], 0, 0, 0); \
            acc[mi][(NH_) * 2 + 1] = __builtin_amdgcn_mfma_f32_16x16x32_f16(av[mi], bv1, acc[mi][(NH_) * 2 + 1], 0, 0, 0); } \
        __builtin_amdgcn_s_setprio(0); \
        asm volatile("s_waitcnt lgkmcnt(0)" ::: "memory"); \
        __builtin_amdgcn_sched_barrier(0); \
        if (GATE_) { asm volatile("s_waitcnt vmcnt(4)" ::: "memory"); __builtin_amdgcn_sched_barrier(0); } \
        __builtin_amdgcn_s_barrier(); }

    STAGE(0, 1, 0); STAGE(0, 0, 0); STAGE(0, 1, 1); STAGE(0, 0, 1);
    STAGE(1, 1, 0); STAGE(1, 0, 0);
    asm volatile("s_waitcnt vmcnt(4)" ::: "memory");
    __builtin_amdgcn_sched_barrier(0);
    __builtin_amdgcn_s_barrier();

    for (int i = 0; i < nt / 2; ++i) {
        const int t0 = 2 * i;
        PHASE(0, 0, 0, 1, t0 + 1, 1, 1, 0)
        PHASE(0, 0, 1, 0, t0 + 1, 0, 1, 0)
        PHASE(0, 1, 0, 1, t0 + 2, 1, 0, 0)
        PHASE(0, 1, 1, 0, t0 + 2, 0, 0, 1)
        PHASE(1, 0, 0, 1, t0 + 2, 1, 1, 0)
        PHASE(1, 0, 1, 0, t0 + 2, 0, 1, 0)
        PHASE(1, 1, 0, 1, t0 + 3, 1, 0, 0)
        PHASE(1, 1, 1, 0, t0 + 3, 0, 0, 1)
    }
#undef PHASE
#undef LDA8

    asm volatile("s_waitcnt vmcnt(0) lgkmcnt(0)" ::: "memory");
    __builtin_amdgcn_sched_barrier(0);
    __builtin_amdgcn_s_barrier();

    ushort* ws = lds + wid * 8192;
#pragma unroll
    for (int ni = 0; ni < 4; ++ni) {
        const int col = n0 + wn * 64 + ni * 16 + fr;
        float addv, mul;
        if (col < 768)       { addv = b_q[col]; mul = SCALE; }
        else if (col < 1536) { addv = 0.f; mul = 1.f; }
        else                 { addv = b_v[col - 1536]; mul = 1.f; }
#pragma unroll
        for (int mi = 0; mi < 8; ++mi)
#pragma unroll
            for (int r = 0; r < 4; ++r)
                ws[(mi * 16 + fg * 4 + r) * 64 + ni * 16 + fr] = f2h_bits((acc[mi][ni][r] + addv) * mul);
    }
    __syncthreads();
#pragma unroll
    for (int it = 0; it < 16; ++it) {
        const int g = it * 64 + lane;
        const int r = g >> 3, seg = g & 7;
        const int row = m0 + wm * 128 + r;
        uint4 v = *(const uint4*)(ws + r * 64 + seg * 8);
        if (row < M) *(uint4*)(outp + (size_t)row * N + n0 + wn * 64 + seg * 8) = v;
    }
}

// ---------------- 128x128 BT GEMM, BK=32, dbuf, XOR-swizzled + XCD swizzle (proj) ----------------
template<int EPI>
__global__ __launch_bounds__(256) void k_gemm(const ushort* __restrict__ A, const ushort* __restrict__ BT,
                                              int M, int N, int K, int nwg,
                                              const float* __restrict__ b_q, const float* __restrict__ b_v,
                                              const float* __restrict__ b_p,
                                              ushort* __restrict__ out_h, float* __restrict__ out_f) {
    __shared__ __align__(16) ushort lds[2][8192];
    const int tid = threadIdx.x, wid = tid >> 6, lane = tid & 63;
    const int wm = wid >> 1, wn = wid & 1;
    const int fr = lane & 15, fg = lane >> 4;
    const int nbx = N / 128;
    const int bid = xcd_swz(blockIdx.y * nbx + blockIdx.x, nwg);
    const int m0 = (bid / nbx) * 128, n0 = (bid % nbx) * 128;

    int rA[2], rB[2], cs[2], dst[2];
#pragma unroll
    for (int i = 0; i < 2; ++i) {
        const int g = (wid * 2 + i) * 64 + lane;
        const int row = g >> 2, sp = g & 3;
        cs[i]  = (sp ^ ((row >> 1) & 3)) * 8;
        dst[i] = (wid * 2 + i) * 512;
        const int ra = m0 + row;
        rA[i] = ra < M ? ra : M - 1;
        rB[i] = n0 + row;
    }

    f32x4 acc[4][4] = {};
    const int nt = K / 32;

    auto stage = [&](int t, int buf) {
#pragma unroll
        for (int i = 0; i < 2; ++i)
            gload16(A + (size_t)rA[i] * K + t * 32 + cs[i], &lds[buf][dst[i]]);
#pragma unroll
        for (int i = 0; i < 2; ++i)
            gload16(BT + (size_t)rB[i] * K + t * 32 + cs[i], &lds[buf][4096 + dst[i]]);
    };

    stage(0, 0);
    __syncthreads();
    for (int t = 0; t < nt; ++t) {
        const int cur = t & 1;
        if (t + 1 < nt) stage(t + 1, cur ^ 1);
        const ushort* As = lds[cur];
        const ushort* Bs = lds[cur] + 4096;
        f16x8 af[4], bf[4];
#pragma unroll
        for (int i = 0; i < 4; ++i) {
            const int r = wm * 64 + i * 16 + fr;
            af[i] = *(const f16x8*)(As + r * 32 + ((fg ^ ((r >> 1) & 3)) * 8));
        }
#pragma unroll
        for (int i = 0; i < 4; ++i) {
            const int c = wn * 64 + i * 16 + fr;
            bf[i] = *(const f16x8*)(Bs + c * 32 + ((fg ^ ((c >> 1) & 3)) * 8));
        }
#pragma unroll
        for (int mi = 0; mi < 4; ++mi)
#pragma unroll
            for (int ni = 0; ni < 4; ++ni)
                acc[mi][ni] = __builtin_amdgcn_mfma_f32_16x16x32_f16(af[mi], bf[ni], acc[mi][ni], 0, 0, 0);
        __syncthreads();
    }

#pragma unroll
    for (int ni = 0; ni < 4; ++ni) {
        const int col = n0 + wn * 64 + ni * 16 + fr;
        float addv = 0.f, mul = 1.f;
        if (EPI == 0) {
            if (col < 768)       { addv = b_q[col]; mul = SCALE; }
            else if (col < 1536) { addv = 0.f; }
            else                 { addv = b_v[col - 1536]; }
        } else {
            addv = b_p[col];
        }
#pragma unroll
        for (int mi = 0; mi < 4; ++mi) {
#pragma unroll
            for (int r = 0; r < 4; ++r) {
                const int row = m0 + wm * 64 + mi * 16 + fg * 4 + r;
                if (row < M) {
                    float v = (acc[mi][ni][r] + addv) * mul;
                    if (EPI == 0) out_h[(size_t)row * N + col] = f2h_bits(v);
                    else          out_f[(size_t)row * N + col] = v;
                }
            }
        }
    }
}

// ================ fused attention v3: block=(b,h), 8 waves, conflict-free LDS ================
__global__ __launch_bounds__(512) void k_attn(const ushort* __restrict__ qkv,
                                              const ushort* __restrict__ biash, ushort* __restrict__ out) {
    extern __shared__ ushort sm[];
    ushort* kp  = sm;
    ushort* vts = sm + KP_SZ;
    ushort* ps  = sm + KP_SZ + VTS_SZ;
    const int tid = threadIdx.x, wid = tid >> 6, lane = tid & 63;
    const int fr = lane & 15, fg = lane >> 4;
    const int bh = blockIdx.x;
    const int b = bh / NH, h = bh % NH;
    const size_t qb = (size_t)(b * NTOK) * 2304;
    const int swz8 = (fg ^ ((fr >> 1) & 3)) * 8;

    ushort* vtile = ps;
    for (int t = tid; t < NPAD * 8; t += 512) {
        const int row = t >> 3, seg = t & 7;
        uint4 kv = make_uint4(0u, 0u, 0u, 0u), vv = make_uint4(0u, 0u, 0u, 0u);
        if (row < NTOK) {
            const ushort* src = qkv + qb + (size_t)row * 2304 + 768 + h * 64;
            kv = *reinterpret_cast<const uint4*>(src + seg * 8);
            vv = *reinterpret_cast<const uint4*>(src + 768 + seg * 8);
        }
        const int pcg = (seg & 3) ^ ((row >> 1) & 3);
        *reinterpret_cast<uint4*>(kp + (seg >> 2) * (NPAD * 32) + row * 32 + pcg * 8) = kv;
        *reinterpret_cast<uint4*>(vtile + row * 72 + seg * 8) = vv;
    }
    __syncthreads();
    for (int o = tid; o < 7 * 64 * 4; o += 512) {
        const int kc = o >> 8, rem = o & 255, d = rem >> 2, pcg = rem & 3;
        const int k0 = kc * 32 + (pcg ^ ((d >> 1) & 3)) * 8;
        ushort w[8];
#pragma unroll
        for (int e = 0; e < 8; ++e) w[e] = vtile[(k0 + e) * 72 + d];
        uint4 val;
        val.x = (uint)w[0] | ((uint)w[1] << 16);
        val.y = (uint)w[2] | ((uint)w[3] << 16);
        val.z = (uint)w[4] | ((uint)w[5] << 16);
        val.w = (uint)w[6] | ((uint)w[7] << 16);
        *reinterpret_cast<uint4*>(vts + kc * 2048 + d * 32 + pcg * 8) = val;
    }
    __syncthreads();

    ushort* pw = ps + wid * PW_SZ;

    for (int s = wid; s < 13; s += 8) {
        const int q0 = s * 16;
        f16x8 qf[2];
        {
            int row = q0 + fr;
            row = row < NTOK ? row : NTOK - 1;
            const ushort* qp = qkv + qb + (size_t)row * 2304 + h * 64 + fg * 8;
            qf[0] = *reinterpret_cast<const f16x8*>(qp);
            qf[1] = *reinterpret_cast<const f16x8*>(qp + 32);
        }
        f32x4 sacc[14] = {};
#pragma unroll
        for (int j = 0; j < 14; ++j) {
#pragma unroll
            for (int kh = 0; kh < 2; ++kh) {
                f16x8 kf = *reinterpret_cast<const f16x8*>(kp + kh * (NPAD * 32) + (j * 16 + fr) * 32 + swz8);
                sacc[j] = __builtin_amdgcn_mfma_f32_16x16x32_f16(qf[kh], kf, sacc[j], 0, 0, 0);
            }
        }
        float rs4[4];
#pragma unroll
        for (int r = 0; r < 4; ++r) {
            const int qrow_l = fg * 4 + r;
            int qrow = q0 + qrow_l;
            qrow = qrow < NTOK ? qrow : NTOK - 1;
            const ushort* bp16 = biash + (((size_t)(h * NPAD + qrow) * 16 + fr) << 4);
            f16x8 bv0 = *reinterpret_cast<const f16x8*>(bp16);
            f16x8 bv1 = *reinterpret_cast<const f16x8*>(bp16 + 8);
            float mx = -1e30f;
#pragma unroll
            for (int j = 0; j < 14; ++j) {
                const float bj = (float)(j < 8 ? bv0[j] : bv1[j - 8]);
                float v = sacc[j][r] + bj;
                sacc[j][r] = v;
                mx = fmaxf(mx, v);
            }
            mx = fmaxf(mx, __shfl_xor(mx, 1));
            mx = fmaxf(mx, __shfl_xor(mx, 2));
            mx = fmaxf(mx, __shfl_xor(mx, 4));
            mx = fmaxf(mx, __shfl_xor(mx, 8));
            float sum = 0.f;
            ushort* prow = pw + qrow_l * P_LD;
#pragma unroll
            for (int j = 0; j < 14; ++j) {
                float p = __expf(sacc[j][r] - mx);
                sum += p;
                prow[j * 16 + fr] = f2h_bits(p);
            }
            sum += __shfl_xor(sum, 1);
            sum += __shfl_xor(sum, 2);
            sum += __shfl_xor(sum, 4);
            sum += __shfl_xor(sum, 8);
            rs4[r] = sum;
        }
        f32x4 o[4] = {};
#pragma unroll
        for (int kc = 0; kc < 7; ++kc) {
            f16x8 af = *reinterpret_cast<const f16x8*>(pw + fr * P_LD + kc * 32 + fg * 8);
#pragma unroll
            for (int dt = 0; dt < 4; ++dt) {
                f16x8 bv = *reinterpret_cast<const f16x8*>(vts + kc * 2048 + (dt * 16 + fr) * 32 + swz8);
                o[dt] = __builtin_amdgcn_mfma_f32_16x16x32_f16(af, bv, o[dt], 0, 0, 0);
            }
        }
#pragma unroll
        for (int dt = 0; dt < 4; ++dt) {
#pragma unroll
            for (int r = 0; r < 4; ++r) {
                const int qrow = q0 + fg * 4 + r;
                if (qrow < NTOK) {
                    const float val = o[dt][r] / rs4[r];
                    out[(size_t)(b * NTOK + qrow) * DIM + h * 64 + dt * 16 + fr] = f2h_bits(val);
                }
            }
        }
    }
}

extern "C" void kernel_launch(void* const* d_in, const int* in_sizes, int n_in,
                              void* d_out, int out_size, void* d_ws, size_t ws_size,
                              hipStream_t stream) {
    const float* x         = (const float*)d_in[0];
    const float* Wqkv      = (const float*)d_in[1];
    const float* q_bias    = (const float*)d_in[2];
    const float* v_bias    = (const float*)d_in[3];
    const float* rel_table = (const float*)d_in[4];
    const float* Wproj     = (const float*)d_in[5];
    const float* bproj     = (const float*)d_in[6];
    const int*   rel_index = (const int*)d_in[7];
    float* out = (float*)d_out;

    char* p = (char*)d_ws;
    auto alloc = [&](size_t bytes) { char* r = p; p += (bytes + 255) & ~(size_t)255; return r; };
    ushort* xb     = (ushort*)alloc((size_t)M_TOK * DIM * 2);
    ushort* wqkvb  = (ushort*)alloc((size_t)2304 * 768 * 2);
    ushort* wprojb = (ushort*)alloc((size_t)768 * 768 * 2);
    ushort* qkvb   = (ushort*)alloc((size_t)M_TOK * 2304 * 2);
    ushort* biasb  = (ushort*)alloc((size_t)NH * NPAD * 256 * 2);
    ushort* aob    = (ushort*)alloc((size_t)M_TOK * DIM * 2);

    (void)hipFuncSetAttribute((const void*)k_qkv8, hipFuncAttributeMaxDynamicSharedMemorySize, 131072);
    (void)hipFuncSetAttribute((const void*)k_attn, hipFuncAttributeMaxDynamicSharedMemorySize, ATTN_LDS);

    const int n0 = M_TOK * DIM / 4, n1 = 2304 * 768 / 4, n2 = 768 * 768 / 4;
    k_cvt3<<<(n0 + n1 + n2 + 255) / 256, 256, 0, stream>>>(x, xb, n0, Wqkv, wqkvb, n1, Wproj, wprojb, n2);
    int nbias = NH * NPAD * 256;
    k_bias<<<(nbias + 255) / 256, 256, 0, stream>>>(rel_table, rel_index, biasb);

    k_qkv8<<<dim3(2304 / 256, (M_TOK + 255) / 256), 512, 131072, stream>>>(
        xb, wqkvb, q_bias, v_bias, qkvb);
    k_attn<<<dim3(NB * NH), 512, ATTN_LDS, stream>>>(qkvb, biasb, aob);
    k_gemm<1><<<dim3(768 / 128, (M_TOK + 127) / 128), 256, 0, stream>>>(
        aob, wprojb, M_TOK, 768, 768, (768 / 128) * ((M_TOK + 127) / 128),
        nullptr, nullptr, bproj, nullptr, out);
}